// Round 2
// baseline (4116.821 us; speedup 1.0000x reference)
//
#include <hip/hip_runtime.h>
#include <hip/hip_bf16.h>
#include <math.h>

// ---------------------------------------------------------------------------
// Mamba2 block forward. bf16 intermediate storage, fp32 in-register math.
// b=4, L=4096, D_MODEL=1024, D_INNER=2048, D_STATE=128, N_HEADS=32, HEAD_DIM=64
// CONV_DIM=2304, D_IN_PROJ=4384, CHUNK=64
//
// ws layout (221.3 MB total -- keep under harness ws_size):
//   zx_bf : bf16[16384][4384]   143,654,912 B   (z | xBC_pre | dt_raw)
//   xBC_bf: bf16[16384][2304]    75,497,472 B   (post conv+silu)
//   dt_sp : f32 [16384][32]       2,097,152 B
// y (bf16) is written over zx cols [2048,4096) after conv consumed xBC_pre;
// gate+rmsnorm rewrites that region in place; out_proj reads it.
// Padding: 4096 % 64 == 0; the reference's extra zero chunk only affects
// truncated rows / discarded final_state -> process exactly 64 chunks/batch.
// ---------------------------------------------------------------------------

#define BL    16384
#define LDZX  4384
#define NCONV 2304

typedef __hip_bfloat16 bf16;

union BF8 { uint4 u; bf16 h[8]; };
union BF4 { uint2 u; bf16 h[4]; };

// ---------------- tiled GEMM:  C[m,n] = sum_k A[m,k] * B[n,k] ---------------
// A: fp32 or bf16 (TA). B: fp32. C: fp32 or bf16 (TC). fp32 accumulate.
template<typename TA, typename TC>
__global__ __launch_bounds__(256) void gemm_nt(
    const TA* __restrict__ A, int lda,
    const float* __restrict__ B, int ldb,
    TC* __restrict__ C, int ldc,
    int M, int N, int K)
{
  __shared__ float As[16][132];
  __shared__ float Bs[16][132];
  const int tid = threadIdx.x;
  const int bm = blockIdx.y * 128;
  const int bn = blockIdx.x * 128;
  const int tx = tid & 15, ty = tid >> 4;
  const int m0 = ty * 8, n0 = tx * 8;
  float acc[8][8];
  #pragma unroll
  for (int i = 0; i < 8; ++i)
    #pragma unroll
    for (int j = 0; j < 8; ++j) acc[i][j] = 0.f;

  for (int k0 = 0; k0 < K; k0 += 16) {
    // stage A tile (128 rows x 16 k)
    if constexpr (sizeof(TA) == 4) {
      #pragma unroll
      for (int t = 0; t < 2; ++t) {
        int i = tid + t * 256;               // < 512
        int r = i >> 2, kq = i & 3;
        float4 av = *(const float4*)((const float*)A + (size_t)(bm + r) * lda + (k0 + kq * 4));
        As[kq*4+0][r] = av.x; As[kq*4+1][r] = av.y;
        As[kq*4+2][r] = av.z; As[kq*4+3][r] = av.w;
      }
    } else {
      int r = tid >> 1, kq = tid & 1;        // 256 loads x 8 bf16
      BF8 av; av.u = *(const uint4*)((const bf16*)A + (size_t)(bm + r) * lda + (k0 + kq * 8));
      #pragma unroll
      for (int j = 0; j < 8; ++j) As[kq*8+j][r] = __bfloat162float(av.h[j]);
    }
    // stage B tile (128 rows x 16 k), guard rows >= N
    #pragma unroll
    for (int t = 0; t < 2; ++t) {
      int i = tid + t * 256;
      int r = i >> 2, kq = i & 3;
      float4 bv = make_float4(0.f, 0.f, 0.f, 0.f);
      int n = bn + r;
      if (n < N) bv = *(const float4*)(B + (size_t)n * ldb + (k0 + kq * 4));
      Bs[kq*4+0][r] = bv.x; Bs[kq*4+1][r] = bv.y;
      Bs[kq*4+2][r] = bv.z; Bs[kq*4+3][r] = bv.w;
    }
    __syncthreads();
    #pragma unroll
    for (int kk = 0; kk < 16; ++kk) {
      float a[8], b[8];
      *(float4*)&a[0] = *(const float4*)&As[kk][m0];
      *(float4*)&a[4] = *(const float4*)&As[kk][m0 + 4];
      *(float4*)&b[0] = *(const float4*)&Bs[kk][n0];
      *(float4*)&b[4] = *(const float4*)&Bs[kk][n0 + 4];
      #pragma unroll
      for (int i = 0; i < 8; ++i)
        #pragma unroll
        for (int j = 0; j < 8; ++j)
          acc[i][j] += a[i] * b[j];
    }
    __syncthreads();
  }
  #pragma unroll
  for (int i = 0; i < 8; ++i) {
    int m = bm + m0 + i;
    #pragma unroll
    for (int j4 = 0; j4 < 2; ++j4) {
      int n = bn + n0 + j4 * 4;
      if (n < N) {
        if constexpr (sizeof(TC) == 4) {
          float4 o = make_float4(acc[i][j4*4+0], acc[i][j4*4+1],
                                 acc[i][j4*4+2], acc[i][j4*4+3]);
          *(float4*)((float*)C + (size_t)m * ldc + n) = o;
        } else {
          BF4 o;
          #pragma unroll
          for (int j = 0; j < 4; ++j) o.h[j] = __float2bfloat16(acc[i][j4*4+j]);
          *(uint2*)((bf16*)C + (size_t)m * ldc + n) = o.u;
        }
      }
    }
  }
}

// ---------------- dt = softplus(raw + bias) --------------------------------
__global__ __launch_bounds__(256) void dtsp_kernel(
    const bf16* __restrict__ zx, const float* __restrict__ dt_bias,
    float* __restrict__ dt_sp)
{
  int idx = blockIdx.x * 256 + threadIdx.x;      // < 16384*32
  int row = idx >> 5, h = idx & 31;
  float v = __bfloat162float(zx[(size_t)row * LDZX + 4352 + h]) + dt_bias[h];
  dt_sp[idx] = fmaxf(v, 0.f) + log1pf(expf(-fabsf(v)));
}

// ---------------- depthwise causal conv(4) + bias + silu -------------------
__global__ __launch_bounds__(256) void conv_silu_kernel(
    const bf16* __restrict__ zx,       // xBC_pre at col 2048, ld 4384
    const float* __restrict__ conv_w,  // (2304*4)
    const float* __restrict__ conv_b,  // (2304)
    bf16* __restrict__ xBC)            // (BL, 2304)
{
  const int ch = blockIdx.x * 256 + threadIdx.x; // < 2304
  const int t0 = blockIdx.y * 8;
  const int bb = blockIdx.z;
  const float w0 = conv_w[ch*4+0], w1 = conv_w[ch*4+1];
  const float w2 = conv_w[ch*4+2], w3 = conv_w[ch*4+3];
  const float bias = conv_b[ch];
  const size_t rb = (size_t)bb * 4096;
  const bf16* src = zx + 2048 + ch;
  float v0 = (t0 >= 3) ? __bfloat162float(src[(rb + t0 - 3) * LDZX]) : 0.f;
  float v1 = (t0 >= 2) ? __bfloat162float(src[(rb + t0 - 2) * LDZX]) : 0.f;
  float v2 = (t0 >= 1) ? __bfloat162float(src[(rb + t0 - 1) * LDZX]) : 0.f;
  for (int t = t0; t < t0 + 8; ++t) {
    float v3 = __bfloat162float(src[(rb + t) * LDZX]);
    float o = bias + w0*v0 + w1*v1 + w2*v2 + w3*v3;
    o = o / (1.f + expf(-o));                    // silu
    xBC[(rb + t) * NCONV + ch] = __float2bfloat16(o);
    v0 = v1; v1 = v2; v2 = v3;
  }
}

// ---------------- fused chunked SSD scan -----------------------------------
// grid (2 p-halves, 32 heads, 4 batches), 256 threads. One block per CU.
__global__ __launch_bounds__(256) void ssd_kernel(
    const bf16* __restrict__ xBC,     // (BL, 2304) post conv+silu
    const float* __restrict__ dt_sp,  // (BL, 32)
    const float* __restrict__ A_log,  // (32)
    const float* __restrict__ Dp,     // (32)
    bf16* __restrict__ Y, int ldy)    // zx + 2048, ld 4384
{
  const int ph = blockIdx.x;   // p-half: cols ph*32 .. +32 of head
  const int hh = blockIdx.y;
  const int bb = blockIdx.z;
  const int tid = threadIdx.x;

  __shared__ float Bs[64][132];   // B chunk  [token][n]
  __shared__ float Cs[64][132];   // C chunk
  __shared__ float xs[64][32];    // x chunk  [token][p] (raw, no dt)
  __shared__ float sc[64][65];    // scores   [l][s] (decay*dt folded in)
  __shared__ float st[32][132];   // running state [p][n]
  __shared__ float Ac[64], dts[64], sl[64], dko[64];

  const float Ah = -expf(A_log[hh]);
  const float Dh = Dp[hh];
  const int xcol = hh * 64 + ph * 32;
  const size_t rowbase = (size_t)bb * 4096;

  for (int i = tid; i < 32 * 132; i += 256) (&st[0][0])[i] = 0.f;
  __syncthreads();

  for (int c = 0; c < 64; ++c) {
    const size_t r0 = rowbase + (size_t)c * 64;
    // ---- stage chunk into LDS (bf16 -> fp32) ----
    #pragma unroll
    for (int t = 0; t < 4; ++t) {
      int i = tid + t * 256;                 // < 1024
      int rr = i >> 4, c8 = i & 15;
      const bf16* rowp = xBC + (r0 + rr) * NCONV;
      BF8 bv; bv.u = *(const uint4*)(rowp + 2048 + c8*8);
      BF8 cv; cv.u = *(const uint4*)(rowp + 2176 + c8*8);
      #pragma unroll
      for (int j = 0; j < 8; ++j) {
        Bs[rr][c8*8+j] = __bfloat162float(bv.h[j]);
        Cs[rr][c8*8+j] = __bfloat162float(cv.h[j]);
      }
    }
    {
      int rr = tid >> 2, c8 = tid & 3;       // 64 x 32
      BF8 xv; xv.u = *(const uint4*)(xBC + (r0 + rr) * NCONV + xcol + c8*8);
      #pragma unroll
      for (int j = 0; j < 8; ++j) xs[rr][c8*8+j] = __bfloat162float(xv.h[j]);
    }
    if (tid < 64) {                          // dt + inclusive cumsum of a=A*dt
      float d = dt_sp[(r0 + tid) * 32 + hh];
      dts[tid] = d;
      float v = Ah * d;
      #pragma unroll
      for (int off = 1; off < 64; off <<= 1) {
        float up = __shfl_up(v, off, 64);
        if (tid >= off) v += up;
      }
      Ac[tid] = v;
    }
    __syncthreads();
    const float Atot = Ac[63];
    if (tid < 64) {
      sl[tid]  = dts[tid] * expf(Atot - Ac[tid]);  // local-state weight
      dko[tid] = expf(Ac[tid]);                    // state_decay_out
    }
    // ---- scores[l][s] = (C_l . B_s) * exp(Ac_l - Ac_s) * dt_s  (s<=l) ----
    {
      const int l = tid & 63;
      const int s0 = (tid >> 6) << 4;
      float dot[16];
      #pragma unroll
      for (int i = 0; i < 16; ++i) dot[i] = 0.f;
      for (int n4 = 0; n4 < 32; ++n4) {
        const float4 cv = *(const float4*)&Cs[l][n4*4];
        #pragma unroll
        for (int si = 0; si < 16; ++si) {
          const float4 bv = *(const float4*)&Bs[s0 + si][n4*4];
          dot[si] += cv.x*bv.x + cv.y*bv.y + cv.z*bv.z + cv.w*bv.w;
        }
      }
      const float acl = Ac[l];
      #pragma unroll
      for (int si = 0; si < 16; ++si) {
        int s = s0 + si;
        sc[l][s] = (s <= l) ? dot[si] * expf(acl - Ac[s]) * dts[s] : 0.f;
      }
    }
    __syncthreads();
    // ---- Y[l][p] = dko_l * sum_n C_ln * st_pn  +  sum_s sc_ls * x_sp + D*x_lp
    {
      const int l = tid & 63;
      const int pb = (tid >> 6) << 3;
      float offs[8], y[8];
      #pragma unroll
      for (int j = 0; j < 8; ++j) offs[j] = 0.f;
      for (int n4 = 0; n4 < 32; ++n4) {
        const float4 cv = *(const float4*)&Cs[l][n4*4];
        #pragma unroll
        for (int j = 0; j < 8; ++j) {
          const float4 sv = *(const float4*)&st[pb + j][n4*4];
          offs[j] += cv.x*sv.x + cv.y*sv.y + cv.z*sv.z + cv.w*sv.w;
        }
      }
      const float dl = dko[l];
      #pragma unroll
      for (int j = 0; j < 8; ++j) y[j] = dl * offs[j] + Dh * xs[l][pb + j];
      for (int s = 0; s < 64; ++s) {
        const float w = sc[l][s];
        const float4 xa = *(const float4*)&xs[s][pb];
        const float4 xb = *(const float4*)&xs[s][pb + 4];
        y[0] += w*xa.x; y[1] += w*xa.y; y[2] += w*xa.z; y[3] += w*xa.w;
        y[4] += w*xb.x; y[5] += w*xb.y; y[6] += w*xb.z; y[7] += w*xb.w;
      }
      BF8 o;
      #pragma unroll
      for (int j = 0; j < 8; ++j) o.h[j] = __float2bfloat16(y[j]);
      *(uint4*)(Y + (r0 + l) * (size_t)ldy + (xcol + pb)) = o.u;
    }
    __syncthreads();
    // ---- state[p][n] = exp(Atot)*state + sum_l B_ln * sl_l * x_lp ----
    {
      const int p = tid & 31;
      const int nb = (tid >> 5) << 4;
      const float cd = expf(Atot);
      float sreg[16];
      #pragma unroll
      for (int q = 0; q < 4; ++q) {
        float4 sv = *(const float4*)&st[p][nb + q*4];
        sreg[q*4+0] = sv.x*cd; sreg[q*4+1] = sv.y*cd;
        sreg[q*4+2] = sv.z*cd; sreg[q*4+3] = sv.w*cd;
      }
      for (int ll = 0; ll < 64; ++ll) {
        const float xv = xs[ll][p] * sl[ll];
        #pragma unroll
        for (int q = 0; q < 4; ++q) {
          const float4 bv = *(const float4*)&Bs[ll][nb + q*4];
          sreg[q*4+0] += bv.x*xv; sreg[q*4+1] += bv.y*xv;
          sreg[q*4+2] += bv.z*xv; sreg[q*4+3] += bv.w*xv;
        }
      }
      #pragma unroll
      for (int q = 0; q < 4; ++q)
        *(float4*)&st[p][nb + q*4] = make_float4(sreg[q*4+0], sreg[q*4+1],
                                                 sreg[q*4+2], sreg[q*4+3]);
    }
    __syncthreads();
  }
}

// ---------------- t = rmsnorm(y * silu(z)) * norm_w  (in place over y) -----
__global__ __launch_bounds__(256) void gate_rmsnorm_kernel(
    bf16* __restrict__ zx, const float* __restrict__ norm_w)
{
  const size_t row = blockIdx.x;
  const int tid = threadIdx.x;
  __shared__ float red[4];
  bf16* zr = zx + row * LDZX;
  bf16* yr = zr + 2048;
  BF8 zv, yv;
  zv.u = *(const uint4*)(zr + tid * 8);
  yv.u = *(const uint4*)(yr + tid * 8);
  float t[8];
  float local = 0.f;
  #pragma unroll
  for (int j = 0; j < 8; ++j) {
    float z = __bfloat162float(zv.h[j]);
    float y = __bfloat162float(yv.h[j]);
    float tv = y * (z / (1.f + expf(-z)));
    t[j] = tv;
    local += tv * tv;
  }
  #pragma unroll
  for (int off = 32; off; off >>= 1) local += __shfl_down(local, off, 64);
  if ((tid & 63) == 0) red[tid >> 6] = local;
  __syncthreads();
  const float total = red[0] + red[1] + red[2] + red[3];
  const float scale = rsqrtf(total * (1.f / 2048.f) + 1e-5f);
  BF8 o;
  #pragma unroll
  for (int j = 0; j < 8; ++j)
    o.h[j] = __float2bfloat16(t[j] * scale * norm_w[tid * 8 + j]);
  *(uint4*)(yr + tid * 8) = o.u;
}

// ---------------------------------------------------------------------------
extern "C" void kernel_launch(void* const* d_in, const int* in_sizes, int n_in,
                              void* d_out, int out_size, void* d_ws, size_t ws_size,
                              hipStream_t stream) {
  (void)in_sizes; (void)n_in; (void)out_size; (void)ws_size;
  const float* u          = (const float*)d_in[0];
  const float* in_proj_w  = (const float*)d_in[1];
  const float* conv_w     = (const float*)d_in[2];
  const float* conv_b     = (const float*)d_in[3];
  const float* dt_bias    = (const float*)d_in[4];
  const float* A_log      = (const float*)d_in[5];
  const float* Dp         = (const float*)d_in[6];
  const float* norm_w     = (const float*)d_in[7];
  const float* out_proj_w = (const float*)d_in[8];
  float* out = (float*)d_out;

  char* ws = (char*)d_ws;
  bf16*  zx    = (bf16*)ws;                                   // 16384 x 4384
  bf16*  xBC   = (bf16*)(ws + (size_t)BL * LDZX * 2);         // 16384 x 2304
  float* dt_sp = (float*)(ws + (size_t)BL * LDZX * 2
                             + (size_t)BL * NCONV * 2);       // 16384 x 32

  // 1) in_proj (fp32 in, bf16 out)
  gemm_nt<float, bf16><<<dim3(35, 128), 256, 0, stream>>>(
      u, 1024, in_proj_w, 1024, zx, LDZX, BL, 4384, 1024);
  // 2) dt softplus
  dtsp_kernel<<<dim3(2048), 256, 0, stream>>>(zx, dt_bias, dt_sp);
  // 3) conv + silu
  conv_silu_kernel<<<dim3(9, 512, 4), 256, 0, stream>>>(zx, conv_w, conv_b, xBC);
  // 4) SSD (writes y over zx cols [2048,4096))
  ssd_kernel<<<dim3(2, 32, 4), 256, 0, stream>>>(xBC, dt_sp, A_log, Dp,
                                                 zx + 2048, LDZX);
  // 5) gate + rmsnorm (in place)
  gate_rmsnorm_kernel<<<dim3(BL), 256, 0, stream>>>(zx, norm_w);
  // 6) out_proj (bf16 in, fp32 out)
  gemm_nt<bf16, float><<<dim3(8, 128), 256, 0, stream>>>(
      zx + 2048, LDZX, out_proj_w, 2048, out, 1024, BL, 1024, 2048);
}

// Round 3
// 1708.535 us; speedup vs baseline: 2.4096x; 2.4096x over previous
//
#include <hip/hip_runtime.h>
#include <hip/hip_bf16.h>
#include <math.h>

// ---------------------------------------------------------------------------
// Mamba2 block forward. bf16 storage + bf16 MFMA GEMMs, fp32 accumulate.
// b=4, L=4096, D_MODEL=1024, D_INNER=2048, D_STATE=128, N_HEADS=32, HEAD_DIM=64
// CONV_DIM=2304, D_IN_PROJ=4384 (padded to 4480 for 128-tiles), CHUNK=64
//
// ws layout (234.6 MB):
//   zx      bf16[16384][4384]  143,654,912 B  (z | xBC_pre | dt_raw, then y)
//   xBC     bf16[16384][2304]   75,497,472 B  (u_bf16 aliases its head early)
//   dt_sp   f32 [16384][32]      2,097,152 B
//   w_in_p  bf16[4480][1024]     9,175,040 B  (zero-padded rows >= 4384)
//   w_out   bf16[1024][2048]     4,194,304 B
// ---------------------------------------------------------------------------

#define BL    16384
#define LDZX  4384
#define NCONV 2304

typedef __hip_bfloat16 bf16;
typedef __attribute__((ext_vector_type(8))) short bf16x8_i;  // 8 bf16 in 4 VGPRs
typedef __attribute__((ext_vector_type(4))) float f32x4;

union BF8 { uint4 u; bf16 h[8]; };

__device__ __forceinline__ void gload_lds16(const void* g, void* l) {
  __builtin_amdgcn_global_load_lds(
      (__attribute__((address_space(1))) void*)(uintptr_t)g,
      (__attribute__((address_space(3))) void*)(uint32_t)(uintptr_t)l,
      16, 0, 0);
}

// ---------------- bf16 MFMA GEMM:  C[m,n] = sum_k A[m,k] * B[n,k] ----------
// 128x128 tile, BK=32, 4 waves, 4x4 16x16x32 fragments per wave.
// B must be loadable for all 128 rows of each N-tile (pad B). Store guarded.
template<typename TC>
__global__ __launch_bounds__(256) void gemm_bt_mfma(
    const bf16* __restrict__ A, int lda,
    const bf16* __restrict__ B, int ldb,
    TC* __restrict__ C, int ldc, int N, int K)
{
  __shared__ __align__(16) bf16 As[128 * 32];
  __shared__ __align__(16) bf16 Bs[128 * 32];
  const int tid  = threadIdx.x;
  const int lane = tid & 63;
  const int wid  = tid >> 6;
  const int bm = blockIdx.y * 128;
  const int bn = blockIdx.x * 128;
  const int wr = (wid >> 1) * 64;      // wave row offset in tile
  const int wc = (wid & 1) * 64;       // wave col offset in tile

  f32x4 acc[4][4] = {};

  // k-invariant LDS fragment offsets (bf16 elements)
  int aoff[4], boff[4];
  #pragma unroll
  for (int i = 0; i < 4; ++i) {
    aoff[i] = (wr + i * 16 + (lane & 15)) * 32 + (lane >> 4) * 8;
    boff[i] = (wc + i * 16 + (lane & 15)) * 32 + (lane >> 4) * 8;
  }

  // staging map: thread t covers tile row t>>2, k-cols (t&3)*8..+8
  const int srow = tid >> 2, scol = (tid & 3) * 8;
  const bf16* pA = A + (size_t)(bm + srow) * lda + scol;
  const bf16* pB = B + (size_t)(bn + srow) * ldb + scol;
  const size_t lda64 = (size_t)lda * 64, ldb64 = (size_t)ldb * 64;
  bf16* lA0 = As + wid * 512;          // wave-uniform base, lane x 16B auto
  bf16* lA1 = As + 2048 + wid * 512;
  bf16* lB0 = Bs + wid * 512;
  bf16* lB1 = Bs + 2048 + wid * 512;

  for (int k0 = 0; k0 < K; k0 += 32) {
    gload_lds16(pA,         lA0);
    gload_lds16(pA + lda64, lA1);
    gload_lds16(pB,         lB0);
    gload_lds16(pB + ldb64, lB1);
    pA += 32; pB += 32;
    __syncthreads();                    // drains vmcnt before reads
    bf16x8_i af[4], bfr[4];
    #pragma unroll
    for (int i = 0; i < 4; ++i) {
      af[i]  = *(const bf16x8_i*)(As + aoff[i]);
      bfr[i] = *(const bf16x8_i*)(Bs + boff[i]);
    }
    #pragma unroll
    for (int i = 0; i < 4; ++i)
      #pragma unroll
      for (int j = 0; j < 4; ++j)
        acc[i][j] = __builtin_amdgcn_mfma_f32_16x16x32_bf16(
            af[i], bfr[j], acc[i][j], 0, 0, 0);
    __syncthreads();
  }

  // epilogue: C/D layout col = lane&15, row = (lane>>4)*4 + reg
  const int cr = (lane >> 4) * 4;
  const int cc = lane & 15;
  #pragma unroll
  for (int i = 0; i < 4; ++i) {
    #pragma unroll
    for (int j = 0; j < 4; ++j) {
      const int n = bn + wc + j * 16 + cc;
      if (n < N) {
        #pragma unroll
        for (int r = 0; r < 4; ++r) {
          const int m = bm + wr + i * 16 + cr + r;
          if constexpr (sizeof(TC) == 2)
            ((bf16*)C)[(size_t)m * ldc + n] = __float2bfloat16(acc[i][j][r]);
          else
            ((float*)C)[(size_t)m * ldc + n] = acc[i][j][r];
        }
      }
    }
  }
}

// ---------------- conversion kernels ---------------------------------------
__global__ __launch_bounds__(256) void cvt_f32_bf16(
    const float* __restrict__ in, bf16* __restrict__ out)
{
  const size_t i = (size_t)(blockIdx.x * 256 + threadIdx.x) * 8;
  float4 a = *(const float4*)(in + i);
  float4 b = *(const float4*)(in + i + 4);
  BF8 o;
  o.h[0] = __float2bfloat16(a.x); o.h[1] = __float2bfloat16(a.y);
  o.h[2] = __float2bfloat16(a.z); o.h[3] = __float2bfloat16(a.w);
  o.h[4] = __float2bfloat16(b.x); o.h[5] = __float2bfloat16(b.y);
  o.h[6] = __float2bfloat16(b.z); o.h[7] = __float2bfloat16(b.w);
  *(uint4*)(out + i) = o.u;
}

__global__ __launch_bounds__(256) void cvt_pad_win(
    const float* __restrict__ in, bf16* __restrict__ out)
{
  const int idx = blockIdx.x * 256 + threadIdx.x;   // over 4480*1024/8
  const int row = idx >> 7;
  const int col = (idx & 127) * 8;
  BF8 o;
  if (row < 4384) {
    float4 a = *(const float4*)(in + (size_t)row * 1024 + col);
    float4 b = *(const float4*)(in + (size_t)row * 1024 + col + 4);
    o.h[0] = __float2bfloat16(a.x); o.h[1] = __float2bfloat16(a.y);
    o.h[2] = __float2bfloat16(a.z); o.h[3] = __float2bfloat16(a.w);
    o.h[4] = __float2bfloat16(b.x); o.h[5] = __float2bfloat16(b.y);
    o.h[6] = __float2bfloat16(b.z); o.h[7] = __float2bfloat16(b.w);
  } else {
    o.u = make_uint4(0, 0, 0, 0);
  }
  *(uint4*)(out + (size_t)row * 1024 + col) = o.u;
}

// ---------------- dt = softplus(raw + bias) --------------------------------
__global__ __launch_bounds__(256) void dtsp_kernel(
    const bf16* __restrict__ zx, const float* __restrict__ dt_bias,
    float* __restrict__ dt_sp)
{
  int idx = blockIdx.x * 256 + threadIdx.x;      // < 16384*32
  int row = idx >> 5, h = idx & 31;
  float v = __bfloat162float(zx[(size_t)row * LDZX + 4352 + h]) + dt_bias[h];
  dt_sp[idx] = fmaxf(v, 0.f) + log1pf(expf(-fabsf(v)));
}

// ---------------- depthwise causal conv(4) + bias + silu -------------------
__global__ __launch_bounds__(256) void conv_silu_kernel(
    const bf16* __restrict__ zx,       // xBC_pre at col 2048, ld 4384
    const float* __restrict__ conv_w,  // (2304*4)
    const float* __restrict__ conv_b,  // (2304)
    bf16* __restrict__ xBC)            // (BL, 2304)
{
  const int ch = blockIdx.x * 256 + threadIdx.x; // < 2304
  const int t0 = blockIdx.y * 8;
  const int bb = blockIdx.z;
  const float w0 = conv_w[ch*4+0], w1 = conv_w[ch*4+1];
  const float w2 = conv_w[ch*4+2], w3 = conv_w[ch*4+3];
  const float bias = conv_b[ch];
  const size_t rb = (size_t)bb * 4096;
  const bf16* src = zx + 2048 + ch;
  float v0 = (t0 >= 3) ? __bfloat162float(src[(rb + t0 - 3) * LDZX]) : 0.f;
  float v1 = (t0 >= 2) ? __bfloat162float(src[(rb + t0 - 2) * LDZX]) : 0.f;
  float v2 = (t0 >= 1) ? __bfloat162float(src[(rb + t0 - 1) * LDZX]) : 0.f;
  for (int t = t0; t < t0 + 8; ++t) {
    float v3 = __bfloat162float(src[(rb + t) * LDZX]);
    float o = bias + w0*v0 + w1*v1 + w2*v2 + w3*v3;
    o = o / (1.f + expf(-o));                    // silu
    xBC[(rb + t) * NCONV + ch] = __float2bfloat16(o);
    v0 = v1; v1 = v2; v2 = v3;
  }
}

// ---------------- fused chunked SSD scan -----------------------------------
// grid (2 p-halves, 32 heads, 4 batches), 256 threads. One block per CU.
__global__ __launch_bounds__(256) void ssd_kernel(
    const bf16* __restrict__ xBC,     // (BL, 2304) post conv+silu
    const float* __restrict__ dt_sp,  // (BL, 32)
    const float* __restrict__ A_log,  // (32)
    const float* __restrict__ Dp,     // (32)
    bf16* __restrict__ Y, int ldy)    // zx + 2048, ld 4384
{
  const int ph = blockIdx.x;   // p-half: cols ph*32 .. +32 of head
  const int hh = blockIdx.y;
  const int bb = blockIdx.z;
  const int tid = threadIdx.x;

  __shared__ float Bs[64][132];   // B chunk  [token][n]
  __shared__ float Cs[64][132];   // C chunk
  __shared__ float xs[64][32];    // x chunk  [token][p] (raw, no dt)
  __shared__ float sc[64][65];    // scores   [l][s] (decay*dt folded in)
  __shared__ float st[32][132];   // running state [p][n]
  __shared__ float Ac[64], dts[64], sl[64], dko[64];

  const float Ah = -expf(A_log[hh]);
  const float Dh = Dp[hh];
  const int xcol = hh * 64 + ph * 32;
  const size_t rowbase = (size_t)bb * 4096;

  for (int i = tid; i < 32 * 132; i += 256) (&st[0][0])[i] = 0.f;
  __syncthreads();

  for (int c = 0; c < 64; ++c) {
    const size_t r0 = rowbase + (size_t)c * 64;
    // ---- stage chunk into LDS (bf16 -> fp32) ----
    #pragma unroll
    for (int t = 0; t < 4; ++t) {
      int i = tid + t * 256;                 // < 1024
      int rr = i >> 4, c8 = i & 15;
      const bf16* rowp = xBC + (r0 + rr) * NCONV;
      BF8 bv; bv.u = *(const uint4*)(rowp + 2048 + c8*8);
      BF8 cv; cv.u = *(const uint4*)(rowp + 2176 + c8*8);
      #pragma unroll
      for (int j = 0; j < 8; ++j) {
        Bs[rr][c8*8+j] = __bfloat162float(bv.h[j]);
        Cs[rr][c8*8+j] = __bfloat162float(cv.h[j]);
      }
    }
    {
      int rr = tid >> 2, c8 = tid & 3;       // 64 x 32
      BF8 xv; xv.u = *(const uint4*)(xBC + (r0 + rr) * NCONV + xcol + c8*8);
      #pragma unroll
      for (int j = 0; j < 8; ++j) xs[rr][c8*8+j] = __bfloat162float(xv.h[j]);
    }
    if (tid < 64) {                          // dt + inclusive cumsum of a=A*dt
      float d = dt_sp[(r0 + tid) * 32 + hh];
      dts[tid] = d;
      float v = Ah * d;
      #pragma unroll
      for (int off = 1; off < 64; off <<= 1) {
        float up = __shfl_up(v, off, 64);
        if (tid >= off) v += up;
      }
      Ac[tid] = v;
    }
    __syncthreads();
    const float Atot = Ac[63];
    if (tid < 64) {
      sl[tid]  = dts[tid] * expf(Atot - Ac[tid]);  // local-state weight
      dko[tid] = expf(Ac[tid]);                    // state_decay_out
    }
    // ---- scores[l][s] = (C_l . B_s) * exp(Ac_l - Ac_s) * dt_s  (s<=l) ----
    {
      const int l = tid & 63;
      const int s0 = (tid >> 6) << 4;
      float dot[16];
      #pragma unroll
      for (int i = 0; i < 16; ++i) dot[i] = 0.f;
      for (int n4 = 0; n4 < 32; ++n4) {
        const float4 cv = *(const float4*)&Cs[l][n4*4];
        #pragma unroll
        for (int si = 0; si < 16; ++si) {
          const float4 bv = *(const float4*)&Bs[s0 + si][n4*4];
          dot[si] += cv.x*bv.x + cv.y*bv.y + cv.z*bv.z + cv.w*bv.w;
        }
      }
      const float acl = Ac[l];
      #pragma unroll
      for (int si = 0; si < 16; ++si) {
        int s = s0 + si;
        sc[l][s] = (s <= l) ? dot[si] * expf(acl - Ac[s]) * dts[s] : 0.f;
      }
    }
    __syncthreads();
    // ---- Y[l][p] = dko_l * sum_n C_ln * st_pn  +  sum_s sc_ls * x_sp + D*x_lp
    {
      const int l = tid & 63;
      const int pb = (tid >> 6) << 3;
      float offs[8], y[8];
      #pragma unroll
      for (int j = 0; j < 8; ++j) offs[j] = 0.f;
      for (int n4 = 0; n4 < 32; ++n4) {
        const float4 cv = *(const float4*)&Cs[l][n4*4];
        #pragma unroll
        for (int j = 0; j < 8; ++j) {
          const float4 sv = *(const float4*)&st[pb + j][n4*4];
          offs[j] += cv.x*sv.x + cv.y*sv.y + cv.z*sv.z + cv.w*sv.w;
        }
      }
      const float dl = dko[l];
      #pragma unroll
      for (int j = 0; j < 8; ++j) y[j] = dl * offs[j] + Dh * xs[l][pb + j];
      for (int s = 0; s < 64; ++s) {
        const float w = sc[l][s];
        const float4 xa = *(const float4*)&xs[s][pb];
        const float4 xb = *(const float4*)&xs[s][pb + 4];
        y[0] += w*xa.x; y[1] += w*xa.y; y[2] += w*xa.z; y[3] += w*xa.w;
        y[4] += w*xb.x; y[5] += w*xb.y; y[6] += w*xb.z; y[7] += w*xb.w;
      }
      BF8 o;
      #pragma unroll
      for (int j = 0; j < 8; ++j) o.h[j] = __float2bfloat16(y[j]);
      *(uint4*)(Y + (r0 + l) * (size_t)ldy + (xcol + pb)) = o.u;
    }
    __syncthreads();
    // ---- state[p][n] = exp(Atot)*state + sum_l B_ln * sl_l * x_lp ----
    {
      const int p = tid & 31;
      const int nb = (tid >> 5) << 4;
      const float cd = expf(Atot);
      float sreg[16];
      #pragma unroll
      for (int q = 0; q < 4; ++q) {
        float4 sv = *(const float4*)&st[p][nb + q*4];
        sreg[q*4+0] = sv.x*cd; sreg[q*4+1] = sv.y*cd;
        sreg[q*4+2] = sv.z*cd; sreg[q*4+3] = sv.w*cd;
      }
      for (int ll = 0; ll < 64; ++ll) {
        const float xv = xs[ll][p] * sl[ll];
        #pragma unroll
        for (int q = 0; q < 4; ++q) {
          const float4 bv = *(const float4*)&Bs[ll][nb + q*4];
          sreg[q*4+0] += bv.x*xv; sreg[q*4+1] += bv.y*xv;
          sreg[q*4+2] += bv.z*xv; sreg[q*4+3] += bv.w*xv;
        }
      }
      #pragma unroll
      for (int q = 0; q < 4; ++q)
        *(float4*)&st[p][nb + q*4] = make_float4(sreg[q*4+0], sreg[q*4+1],
                                                 sreg[q*4+2], sreg[q*4+3]);
    }
    __syncthreads();
  }
}

// ---------------- t = rmsnorm(y * silu(z)) * norm_w  (in place over y) -----
__global__ __launch_bounds__(256) void gate_rmsnorm_kernel(
    bf16* __restrict__ zx, const float* __restrict__ norm_w)
{
  const size_t row = blockIdx.x;
  const int tid = threadIdx.x;
  __shared__ float red[4];
  bf16* zr = zx + row * LDZX;
  bf16* yr = zr + 2048;
  BF8 zv, yv;
  zv.u = *(const uint4*)(zr + tid * 8);
  yv.u = *(const uint4*)(yr + tid * 8);
  float t[8];
  float local = 0.f;
  #pragma unroll
  for (int j = 0; j < 8; ++j) {
    float z = __bfloat162float(zv.h[j]);
    float y = __bfloat162float(yv.h[j]);
    float tv = y * (z / (1.f + expf(-z)));
    t[j] = tv;
    local += tv * tv;
  }
  #pragma unroll
  for (int off = 32; off; off >>= 1) local += __shfl_down(local, off, 64);
  if ((tid & 63) == 0) red[tid >> 6] = local;
  __syncthreads();
  const float total = red[0] + red[1] + red[2] + red[3];
  const float scale = rsqrtf(total * (1.f / 2048.f) + 1e-5f);
  BF8 o;
  #pragma unroll
  for (int j = 0; j < 8; ++j)
    o.h[j] = __float2bfloat16(t[j] * scale * norm_w[tid * 8 + j]);
  *(uint4*)(yr + tid * 8) = o.u;
}

// ---------------------------------------------------------------------------
extern "C" void kernel_launch(void* const* d_in, const int* in_sizes, int n_in,
                              void* d_out, int out_size, void* d_ws, size_t ws_size,
                              hipStream_t stream) {
  (void)in_sizes; (void)n_in; (void)out_size; (void)ws_size;
  const float* u          = (const float*)d_in[0];
  const float* in_proj_w  = (const float*)d_in[1];
  const float* conv_w     = (const float*)d_in[2];
  const float* conv_b     = (const float*)d_in[3];
  const float* dt_bias    = (const float*)d_in[4];
  const float* A_log      = (const float*)d_in[5];
  const float* Dp         = (const float*)d_in[6];
  const float* norm_w     = (const float*)d_in[7];
  const float* out_proj_w = (const float*)d_in[8];
  float* out = (float*)d_out;

  char* ws = (char*)d_ws;
  bf16*  zx    = (bf16*)ws;                                   // 16384 x 4384
  bf16*  xBC   = (bf16*)(ws + (size_t)BL * LDZX * 2);         // 16384 x 2304
  bf16*  u_bf  = xBC;                                         // aliased (early)
  float* dt_sp = (float*)(ws + (size_t)BL * LDZX * 2
                             + (size_t)BL * NCONV * 2);       // 16384 x 32
  bf16*  w_in  = (bf16*)((char*)dt_sp + (size_t)BL * 32 * 4); // 4480 x 1024
  bf16*  w_out = w_in + (size_t)4480 * 1024;                  // 1024 x 2048

  // 0) conversions
  cvt_f32_bf16<<<dim3(8192), 256, 0, stream>>>(u, u_bf);            // 16.8M
  cvt_pad_win<<<dim3(2240), 256, 0, stream>>>(in_proj_w, w_in);
  cvt_f32_bf16<<<dim3(1024), 256, 0, stream>>>(out_proj_w, w_out);  // 2.1M
  // 1) in_proj (bf16 MFMA): zx[16384,4384] = u_bf @ w_in^T
  gemm_bt_mfma<bf16><<<dim3(35, 128), 256, 0, stream>>>(
      u_bf, 1024, w_in, 1024, zx, LDZX, 4384, 1024);
  // 2) dt softplus
  dtsp_kernel<<<dim3(2048), 256, 0, stream>>>(zx, dt_bias, dt_sp);
  // 3) conv + silu (overwrites u_bf alias region -- u_bf dead after step 1)
  conv_silu_kernel<<<dim3(9, 512, 4), 256, 0, stream>>>(zx, conv_w, conv_b, xBC);
  // 4) SSD (writes y over zx cols [2048,4096))
  ssd_kernel<<<dim3(2, 32, 4), 256, 0, stream>>>(xBC, dt_sp, A_log, Dp,
                                                 zx + 2048, LDZX);
  // 5) gate + rmsnorm (in place)
  gate_rmsnorm_kernel<<<dim3(BL), 256, 0, stream>>>(zx, norm_w);
  // 6) out_proj (bf16 MFMA, fp32 out): out = t @ w_out^T
  gemm_bt_mfma<float><<<dim3(8, 128), 256, 0, stream>>>(
      zx + 2048, LDZX, w_out, 2048, out, 1024, 1024, 2048);
}

// Round 5
// 629.998 us; speedup vs baseline: 6.5347x; 2.7120x over previous
//
#include <hip/hip_runtime.h>
#include <hip/hip_bf16.h>
#include <math.h>

// ---------------------------------------------------------------------------
// Mamba2 block forward. bf16 storage + MFMA everywhere, fp32 accumulate.
// b=4, L=4096, D_MODEL=1024, D_INNER=2048, D_STATE=128, N_HEADS=32, HEAD_DIM=64
//
// Memory plan (234,455,040 B total <= proven-safe 234.6 MB):
//   u_bf   bf16[16384][1024]  33,554,432  (input, bf16)
//   xpre   bf16[16384][2336]  76,546,048  (xBC_pre | dt_raw; y ld2048 after SSD)
//   xBCc   bf16[16384][2304]  75,497,472  (post conv+silu; z ld2048 after SSD)
//   dtT    f32 [4][32][4096]   2,097,152
//   W_xpre bf16[2336][1024]    4,784,128  (in_proj rows 2048..4384)
//   W_z    bf16[2048][1024]    4,194,304  (in_proj rows 0..2048)
//   w_out  bf16[1024][2048]    4,194,304
//   Atot   f32 [4][64][32]        32,768
//   states bf16[64][32][64][128] 33,554,432  (ONE batch; SSD runs 4 phases)
//
// Order: cvt -> GEMM-X -> dtsp -> conv -> (S1,S2,S3)x4 batches ->
//        GEMM-Z (z over xBCc) -> gate+rmsnorm (t over y) -> GEMM-OUT.
// ---------------------------------------------------------------------------

#define BL    16384
#define NCONV 2304
#define LDXP  2336

typedef __hip_bfloat16 bf16;
typedef __attribute__((ext_vector_type(8))) short bf16x8_i;
typedef __attribute__((ext_vector_type(4))) float f32x4;

union BF8 { uint4 u; bf16 h[8]; };

__device__ __forceinline__ void gload_lds16(const void* g, void* l) {
  __builtin_amdgcn_global_load_lds(
      (__attribute__((address_space(1))) void*)(uintptr_t)g,
      (__attribute__((address_space(3))) void*)(uint32_t)(uintptr_t)l,
      16, 0, 0);
}

// ---------------- bf16 MFMA GEMM:  C[m,n] = sum_k A[m,k] * B[n,k] ----------
// 128x128 tile, BK=32, 4 waves, 4x4 16x16x32 frags. CLAMPB: clamp B staging
// rows to N-1 (reads valid garbage, outputs store-guarded at n<N).
template<typename TC, bool CLAMPB>
__global__ __launch_bounds__(256) void gemm_bt_mfma(
    const bf16* __restrict__ A, int lda,
    const bf16* __restrict__ B, int ldb,
    TC* __restrict__ C, int ldc, int N, int K)
{
  __shared__ __align__(16) bf16 As[128 * 32];
  __shared__ __align__(16) bf16 Bs[128 * 32];
  const int tid  = threadIdx.x;
  const int lane = tid & 63;
  const int wid  = tid >> 6;
  const int bm = blockIdx.y * 128;
  const int bn = blockIdx.x * 128;
  const int wr = (wid >> 1) * 64;
  const int wc = (wid & 1) * 64;

  f32x4 acc[4][4] = {};

  int aoff[4], boff[4];
  #pragma unroll
  for (int i = 0; i < 4; ++i) {
    aoff[i] = (wr + i * 16 + (lane & 15)) * 32 + (lane >> 4) * 8;
    boff[i] = (wc + i * 16 + (lane & 15)) * 32 + (lane >> 4) * 8;
  }

  const int srow = tid >> 2, scol = (tid & 3) * 8;
  int brow0 = bn + srow, brow1 = bn + 64 + srow;
  if (CLAMPB) { brow0 = min(brow0, N - 1); brow1 = min(brow1, N - 1); }
  const bf16* pA0 = A + (size_t)(bm + srow) * lda + scol;
  const bf16* pA1 = pA0 + (size_t)lda * 64;
  const bf16* pB0 = B + (size_t)brow0 * ldb + scol;
  const bf16* pB1 = B + (size_t)brow1 * ldb + scol;
  bf16* lA0 = As + wid * 512;
  bf16* lA1 = As + 2048 + wid * 512;
  bf16* lB0 = Bs + wid * 512;
  bf16* lB1 = Bs + 2048 + wid * 512;

  for (int k0 = 0; k0 < K; k0 += 32) {
    gload_lds16(pA0, lA0);
    gload_lds16(pA1, lA1);
    gload_lds16(pB0, lB0);
    gload_lds16(pB1, lB1);
    pA0 += 32; pA1 += 32; pB0 += 32; pB1 += 32;
    __syncthreads();
    bf16x8_i af[4], bfr[4];
    #pragma unroll
    for (int i = 0; i < 4; ++i) {
      af[i]  = *(const bf16x8_i*)(As + aoff[i]);
      bfr[i] = *(const bf16x8_i*)(Bs + boff[i]);
    }
    #pragma unroll
    for (int i = 0; i < 4; ++i)
      #pragma unroll
      for (int j = 0; j < 4; ++j)
        acc[i][j] = __builtin_amdgcn_mfma_f32_16x16x32_bf16(
            af[i], bfr[j], acc[i][j], 0, 0, 0);
    __syncthreads();
  }

  const int cr = (lane >> 4) * 4;
  const int cc = lane & 15;
  #pragma unroll
  for (int i = 0; i < 4; ++i) {
    #pragma unroll
    for (int j = 0; j < 4; ++j) {
      const int n = bn + wc + j * 16 + cc;
      if (n < N) {
        #pragma unroll
        for (int r = 0; r < 4; ++r) {
          const int m = bm + wr + i * 16 + cr + r;
          if constexpr (sizeof(TC) == 2)
            ((bf16*)C)[(size_t)m * ldc + n] = __float2bfloat16(acc[i][j][r]);
          else
            ((float*)C)[(size_t)m * ldc + n] = acc[i][j][r];
        }
      }
    }
  }
}

// ---------------- conversion -----------------------------------------------
__global__ __launch_bounds__(256) void cvt_f32_bf16(
    const float* __restrict__ in, bf16* __restrict__ out)
{
  const size_t i = (size_t)(blockIdx.x * 256 + threadIdx.x) * 8;
  float4 a = *(const float4*)(in + i);
  float4 b = *(const float4*)(in + i + 4);
  BF8 o;
  o.h[0] = __float2bfloat16(a.x); o.h[1] = __float2bfloat16(a.y);
  o.h[2] = __float2bfloat16(a.z); o.h[3] = __float2bfloat16(a.w);
  o.h[4] = __float2bfloat16(b.x); o.h[5] = __float2bfloat16(b.y);
  o.h[6] = __float2bfloat16(b.z); o.h[7] = __float2bfloat16(b.w);
  *(uint4*)(out + i) = o.u;
}

// ---------------- dt softplus + per-chunk Atot -----------------------------
// grid (64 c, 4 b), 256 thr: h = tid&31, l-group = tid>>5 (8 tokens each)
__global__ __launch_bounds__(256) void dtsp_atot_kernel(
    const bf16* __restrict__ xpre, const float* __restrict__ dt_bias,
    const float* __restrict__ A_log,
    float* __restrict__ dtT, float* __restrict__ Atot)
{
  const int c = blockIdx.x, b = blockIdx.y;
  const int tid = threadIdx.x;
  const int h = tid & 31, lg = tid >> 5;
  __shared__ float red[8][33];
  float s = 0.f, vals[8];
  const bf16* src = xpre + ((size_t)b * 4096 + c * 64 + lg * 8) * LDXP + 2304 + h;
  const float bias = dt_bias[h];
  #pragma unroll
  for (int k = 0; k < 8; ++k) {
    float v = __bfloat162float(src[(size_t)k * LDXP]) + bias;
    v = fmaxf(v, 0.f) + log1pf(expf(-fabsf(v)));
    vals[k] = v; s += v;
  }
  float* dp = dtT + ((size_t)(b * 32 + h)) * 4096 + c * 64 + lg * 8;
  #pragma unroll
  for (int k = 0; k < 8; ++k) dp[k] = vals[k];
  red[lg][h] = s;
  __syncthreads();
  if (tid < 32) {
    float t = 0.f;
    #pragma unroll
    for (int g = 0; g < 8; ++g) t += red[g][tid];
    Atot[((size_t)b * 64 + c) * 32 + tid] = -expf(A_log[tid]) * t;
  }
}

// ---------------- depthwise causal conv(4) + bias + silu -------------------
__global__ __launch_bounds__(256) void conv_silu_kernel(
    const bf16* __restrict__ xpre,
    const float* __restrict__ conv_w,
    const float* __restrict__ conv_b,
    bf16* __restrict__ xBC)
{
  const int ch = blockIdx.x * 256 + threadIdx.x;  // < 2304
  const int t0 = blockIdx.y * 8;
  const int bb = blockIdx.z;
  const float w0 = conv_w[ch*4+0], w1 = conv_w[ch*4+1];
  const float w2 = conv_w[ch*4+2], w3 = conv_w[ch*4+3];
  const float bias = conv_b[ch];
  const size_t rb = (size_t)bb * 4096;
  const bf16* src = xpre + ch;
  float v0 = (t0 >= 3) ? __bfloat162float(src[(rb + t0 - 3) * LDXP]) : 0.f;
  float v1 = (t0 >= 2) ? __bfloat162float(src[(rb + t0 - 2) * LDXP]) : 0.f;
  float v2 = (t0 >= 1) ? __bfloat162float(src[(rb + t0 - 1) * LDXP]) : 0.f;
  for (int t = t0; t < t0 + 8; ++t) {
    float v3 = __bfloat162float(src[(rb + t) * LDXP]);
    float o = bias + w0*v0 + w1*v1 + w2*v2 + w3*v3;
    o = o / (1.f + expf(-o));
    xBC[(rb + t) * NCONV + ch] = __float2bfloat16(o);
    v0 = v1; v1 = v2; v2 = v3;
  }
}

// swizzle helper: XOR the 8-block index of l by low bits of the row
__device__ __forceinline__ int swz8(int row) { return ((row >> 3) & 7) << 3; }

// ---------------- S1: chunk-local states via MFMA --------------------------
// grid (64 c, 32 h), one batch b. S_loc[p][n] = sum_l (w_l x_l[p]) B_l[n]
__global__ __launch_bounds__(256) void s1_localstate(
    const bf16* __restrict__ xBC, const float* __restrict__ dtT,
    const float* __restrict__ A_log, bf16* __restrict__ states, int b)
{
  const int c = blockIdx.x, hh = blockIdx.y;
  const int tid = threadIdx.x, lane = tid & 63, wid = tid >> 6;
  __shared__ bf16 BT[128 * 72];    // [n][l^swz]
  __shared__ bf16 xwT[64 * 72];    // [p][l^swz]
  __shared__ bf16 Sout[64 * 136];  // bounce for coalesced store
  const size_t r0 = (size_t)b * 4096 + (size_t)c * 64;

  BF8 regB[4], regx[2];
  #pragma unroll
  for (int k = 0; k < 4; ++k) {
    int id = tid + k * 256, l = id >> 4, n0 = (id & 15) * 8;
    regB[k].u = *(const uint4*)(xBC + (r0 + l) * NCONV + 2048 + n0);
  }
  #pragma unroll
  for (int k = 0; k < 2; ++k) {
    int id = tid + k * 256, l = id >> 3, p0 = (id & 7) * 8;
    regx[k].u = *(const uint4*)(xBC + (r0 + l) * NCONV + hh * 64 + p0);
  }

  // redundant per-wave cumsum: lane holds token l = lane
  float d = dtT[((size_t)(b * 32 + hh)) * 4096 + c * 64 + lane];
  float Ah = -expf(A_log[hh]);
  float v = Ah * d;
  #pragma unroll
  for (int off = 1; off < 64; off <<= 1) {
    float up = __shfl_up(v, off, 64);
    if (lane >= off) v += up;
  }
  const float At = __shfl(v, 63, 64);
  const float w = d * __expf(At - v);

  #pragma unroll
  for (int k = 0; k < 4; ++k) {
    int id = tid + k * 256, l = id >> 4, n0 = (id & 15) * 8;
    #pragma unroll
    for (int j = 0; j < 8; ++j) {
      int n = n0 + j;
      BT[n * 72 + (l ^ swz8(n))] = regB[k].h[j];
    }
  }
  #pragma unroll
  for (int k = 0; k < 2; ++k) {
    int id = tid + k * 256, l = id >> 3, p0 = (id & 7) * 8;
    float wv = __shfl(w, l, 64);
    #pragma unroll
    for (int j = 0; j < 8; ++j) {
      int p = p0 + j;
      xwT[p * 72 + (l ^ swz8(p))] =
          __float2bfloat16(__bfloat162float(regx[k].h[j]) * wv);
    }
  }
  __syncthreads();

  // MFMA: M=p(64), N=n(128), K=l(64)
  const int wr = (wid & 1) * 32;   // p
  const int wc = (wid >> 1) * 64;  // n
  f32x4 acc[2][4] = {};
  #pragma unroll
  for (int ks = 0; ks < 2; ++ks) {
    const int k0 = ks * 32 + (lane >> 4) * 8;
    bf16x8_i a[2], bb[4];
    #pragma unroll
    for (int i = 0; i < 2; ++i) {
      int p = wr + i * 16 + (lane & 15);
      a[i] = *(const bf16x8_i*)(xwT + p * 72 + (k0 ^ swz8(p)));
    }
    #pragma unroll
    for (int j = 0; j < 4; ++j) {
      int n = wc + j * 16 + (lane & 15);
      bb[j] = *(const bf16x8_i*)(BT + n * 72 + (k0 ^ swz8(n)));
    }
    #pragma unroll
    for (int i = 0; i < 2; ++i)
      #pragma unroll
      for (int j = 0; j < 4; ++j)
        acc[i][j] = __builtin_amdgcn_mfma_f32_16x16x32_bf16(
            a[i], bb[j], acc[i][j], 0, 0, 0);
  }

  const int cr = (lane >> 4) * 4, cn = lane & 15;
  #pragma unroll
  for (int i = 0; i < 2; ++i)
    #pragma unroll
    for (int j = 0; j < 4; ++j)
      #pragma unroll
      for (int r = 0; r < 4; ++r)
        Sout[(wr + i * 16 + cr + r) * 136 + (wc + j * 16 + cn)] =
            __float2bfloat16(acc[i][j][r]);
  __syncthreads();
  bf16* sb = states + ((size_t)c * 32 + hh) * 8192;
  #pragma unroll
  for (int k = 0; k < 4; ++k) {
    int id = tid + k * 256, p = id >> 4, n0 = (id & 15) * 8;
    *(uint4*)(sb + p * 128 + n0) = *(const uint4*)(Sout + p * 136 + n0);
  }
}

// ---------------- S2: in-place scan over chunks (4-deep pipelined) ---------
// grid 128 blocks x 256 thr: block -> (h, p-quarter), thread -> (p, n0/8).
__global__ __launch_bounds__(256) void s2_scan(
    bf16* __restrict__ states, const float* __restrict__ Atot, int b)
{
  const int hp = blockIdx.x >> 2;
  const int p  = ((blockIdx.x & 3) << 4) | (threadIdx.x >> 4);
  const int n0 = (threadIdx.x & 15) * 8;
  __shared__ float ec[64];
  if (threadIdx.x < 64)
    ec[threadIdx.x] = expf(Atot[((size_t)b * 64 + threadIdx.x) * 32 + hp]);
  __syncthreads();
  bf16* ptr = states + ((size_t)hp * 64 + p) * 128 + n0;
  const size_t cs = (size_t)32 * 8192;   // chunk stride
  float carry[8] = {0.f,0.f,0.f,0.f,0.f,0.f,0.f,0.f};
  BF8 g0, g1, g2, g3, n0_, n1_, n2_, n3_;
  g0.u = *(const uint4*)(ptr + 0 * cs);
  g1.u = *(const uint4*)(ptr + 1 * cs);
  g2.u = *(const uint4*)(ptr + 2 * cs);
  g3.u = *(const uint4*)(ptr + 3 * cs);
  for (int g = 0; g < 16; ++g) {
    const int c0 = g * 4;
    if (g < 15) {
      n0_.u = *(const uint4*)(ptr + (c0 + 4) * cs);
      n1_.u = *(const uint4*)(ptr + (c0 + 5) * cs);
      n2_.u = *(const uint4*)(ptr + (c0 + 6) * cs);
      n3_.u = *(const uint4*)(ptr + (c0 + 7) * cs);
    }
    BF8 o0, o1, o2, o3;
    const float e0 = ec[c0], e1 = ec[c0+1], e2 = ec[c0+2], e3 = ec[c0+3];
    #pragma unroll
    for (int j = 0; j < 8; ++j) {
      o0.h[j] = __float2bfloat16(carry[j]);
      carry[j] = fmaf(e0, carry[j], __bfloat162float(g0.h[j]));
      o1.h[j] = __float2bfloat16(carry[j]);
      carry[j] = fmaf(e1, carry[j], __bfloat162float(g1.h[j]));
      o2.h[j] = __float2bfloat16(carry[j]);
      carry[j] = fmaf(e2, carry[j], __bfloat162float(g2.h[j]));
      o3.h[j] = __float2bfloat16(carry[j]);
      carry[j] = fmaf(e3, carry[j], __bfloat162float(g3.h[j]));
    }
    *(uint4*)(ptr + (c0 + 0) * cs) = o0.u;
    *(uint4*)(ptr + (c0 + 1) * cs) = o1.u;
    *(uint4*)(ptr + (c0 + 2) * cs) = o2.u;
    *(uint4*)(ptr + (c0 + 3) * cs) = o3.u;
    g0 = n0_; g1 = n1_; g2 = n2_; g3 = n3_;
  }
}

// ---------------- S3: chunk outputs via MFMA -------------------------------
// grid (64 c, 32 h), one batch b. Y written packed ld 2048.
__global__ __launch_bounds__(256) void s3_output(
    const bf16* __restrict__ xBC, const float* __restrict__ dtT,
    const float* __restrict__ A_log, const float* __restrict__ Dp,
    const bf16* __restrict__ states, bf16* __restrict__ Y, int b)
{
  const int c = blockIdx.x, hh = blockIdx.y;
  const int tid = threadIdx.x, lane = tid & 63, wid = tid >> 6;
  __shared__ bf16 Cc[64 * 136];   // [l][n]
  __shared__ bf16 Bc[64 * 136];   // [s][n]; reused as Yb
  __shared__ bf16 Sin[64 * 136];  // [p][n]
  __shared__ bf16 xT[64 * 72];    // [p][l^swz]
  __shared__ bf16 scb[64 * 72];   // [l][s]
  __shared__ float Ac[64], dts[64];
  const size_t r0 = (size_t)b * 4096 + (size_t)c * 64;

  if (tid < 64) {
    float d = dtT[((size_t)(b * 32 + hh)) * 4096 + c * 64 + tid];
    float Ah = -expf(A_log[hh]);
    float v = Ah * d;
    #pragma unroll
    for (int off = 1; off < 64; off <<= 1) {
      float up = __shfl_up(v, off, 64);
      if (tid >= off) v += up;
    }
    Ac[tid] = v; dts[tid] = d;
  }

  #pragma unroll
  for (int k = 0; k < 4; ++k) {
    int id = tid + k * 256, l = id >> 4, n0 = (id & 15) * 8;
    BF8 bv; bv.u = *(const uint4*)(xBC + (r0 + l) * NCONV + 2048 + n0);
    BF8 cv; cv.u = *(const uint4*)(xBC + (r0 + l) * NCONV + 2176 + n0);
    *(uint4*)(Bc + l * 136 + n0) = bv.u;
    *(uint4*)(Cc + l * 136 + n0) = cv.u;
  }
  const bf16* sb = states + ((size_t)c * 32 + hh) * 8192;
  #pragma unroll
  for (int k = 0; k < 4; ++k) {
    int id = tid + k * 256, p = id >> 4, n0 = (id & 15) * 8;
    *(uint4*)(Sin + p * 136 + n0) = *(const uint4*)(sb + p * 128 + n0);
  }
  #pragma unroll
  for (int k = 0; k < 2; ++k) {
    int id = tid + k * 256, l = id >> 3, p0 = (id & 7) * 8;
    BF8 v; v.u = *(const uint4*)(xBC + (r0 + l) * NCONV + hh * 64 + p0);
    #pragma unroll
    for (int j = 0; j < 8; ++j) {
      int p = p0 + j;
      xT[p * 72 + (l ^ swz8(p))] = v.h[j];
    }
  }
  __syncthreads();

  // scores: M=l, N=s, K=n(128); A-frags (C rows) cached for Y_off reuse
  const int wr  = (wid & 1) * 32;   // l
  const int wcs = (wid >> 1) * 32;  // s / p
  f32x4 as[2][2] = {};
  bf16x8_i afrag[2][4];
  #pragma unroll
  for (int ks = 0; ks < 4; ++ks) {
    const int k0 = ks * 32 + (lane >> 4) * 8;
    #pragma unroll
    for (int i = 0; i < 2; ++i)
      afrag[i][ks] =
          *(const bf16x8_i*)(Cc + (wr + i * 16 + (lane & 15)) * 136 + k0);
    #pragma unroll
    for (int j = 0; j < 2; ++j) {
      bf16x8_i bfr =
          *(const bf16x8_i*)(Bc + (wcs + j * 16 + (lane & 15)) * 136 + k0);
      #pragma unroll
      for (int i = 0; i < 2; ++i)
        as[i][j] = __builtin_amdgcn_mfma_f32_16x16x32_bf16(
            afrag[i][ks], bfr, as[i][j], 0, 0, 0);
    }
  }
  const int cr = (lane >> 4) * 4, cc = lane & 15;
  #pragma unroll
  for (int i = 0; i < 2; ++i) {
    #pragma unroll
    for (int r = 0; r < 4; ++r) {
      const int l = wr + i * 16 + cr + r;
      const float acl = Ac[l];
      #pragma unroll
      for (int j = 0; j < 2; ++j) {
        const int s = wcs + j * 16 + cc;
        float val = (s <= l) ? as[i][j][r] * __expf(acl - Ac[s]) * dts[s] : 0.f;
        scb[l * 72 + s] = __float2bfloat16(val);
      }
    }
  }
  __syncthreads();

  // Y_off = C.S_in^T (K=128) scaled by dko_l, += scores.x (K=64)
  f32x4 ay[2][2] = {};
  #pragma unroll
  for (int ks = 0; ks < 4; ++ks) {
    const int k0 = ks * 32 + (lane >> 4) * 8;
    #pragma unroll
    for (int j = 0; j < 2; ++j) {
      bf16x8_i bfr =
          *(const bf16x8_i*)(Sin + (wcs + j * 16 + (lane & 15)) * 136 + k0);
      #pragma unroll
      for (int i = 0; i < 2; ++i)
        ay[i][j] = __builtin_amdgcn_mfma_f32_16x16x32_bf16(
            afrag[i][ks], bfr, ay[i][j], 0, 0, 0);
    }
  }
  #pragma unroll
  for (int i = 0; i < 2; ++i)
    #pragma unroll
    for (int r = 0; r < 4; ++r) {
      const float dk = __expf(Ac[wr + i * 16 + cr + r]);
      #pragma unroll
      for (int j = 0; j < 2; ++j) ay[i][j][r] *= dk;
    }
  #pragma unroll
  for (int ks = 0; ks < 2; ++ks) {
    const int k0 = ks * 32 + (lane >> 4) * 8;
    bf16x8_i a2[2], b2[2];
    #pragma unroll
    for (int i = 0; i < 2; ++i)
      a2[i] = *(const bf16x8_i*)(scb + (wr + i * 16 + (lane & 15)) * 72 + k0);
    #pragma unroll
    for (int j = 0; j < 2; ++j) {
      int p = wcs + j * 16 + (lane & 15);
      b2[j] = *(const bf16x8_i*)(xT + p * 72 + (k0 ^ swz8(p)));
    }
    #pragma unroll
    for (int i = 0; i < 2; ++i)
      #pragma unroll
      for (int j = 0; j < 2; ++j)
        ay[i][j] = __builtin_amdgcn_mfma_f32_16x16x32_bf16(
            a2[i], b2[j], ay[i][j], 0, 0, 0);
  }
  const float Dh = Dp[hh];
  bf16* Yb = Bc;
  #pragma unroll
  for (int i = 0; i < 2; ++i)
    #pragma unroll
    for (int r = 0; r < 4; ++r) {
      const int l = wr + i * 16 + cr + r;
      #pragma unroll
      for (int j = 0; j < 2; ++j) {
        const int p = wcs + j * 16 + cc;
        float xv = __bfloat162float(xT[p * 72 + (l ^ swz8(p))]);
        Yb[l * 136 + p] = __float2bfloat16(ay[i][j][r] + Dh * xv);
      }
    }
  __syncthreads();
  #pragma unroll
  for (int k = 0; k < 2; ++k) {
    int id = tid + k * 256, l = id >> 3, p0 = (id & 7) * 8;
    *(uint4*)(Y + (r0 + l) * 2048 + hh * 64 + p0) =
        *(const uint4*)(Yb + l * 136 + p0);
  }
}

// ---------------- t = rmsnorm(y * silu(z)) * norm_w  (in place over y) -----
__global__ __launch_bounds__(256) void gate_rmsnorm_kernel(
    bf16* __restrict__ y, const bf16* __restrict__ z,
    const float* __restrict__ norm_w)
{
  const size_t row = blockIdx.x;
  const int tid = threadIdx.x;
  __shared__ float red[4];
  const bf16* zr = z + row * 2048;
  bf16* yr = y + row * 2048;
  BF8 zv, yv;
  zv.u = *(const uint4*)(zr + tid * 8);
  yv.u = *(const uint4*)(yr + tid * 8);
  float t[8];
  float local = 0.f;
  #pragma unroll
  for (int j = 0; j < 8; ++j) {
    float zz = __bfloat162float(zv.h[j]);
    float yy = __bfloat162float(yv.h[j]);
    float tv = yy * (zz / (1.f + expf(-zz)));
    t[j] = tv;
    local += tv * tv;
  }
  #pragma unroll
  for (int off = 32; off; off >>= 1) local += __shfl_down(local, off, 64);
  if ((tid & 63) == 0) red[tid >> 6] = local;
  __syncthreads();
  const float total = red[0] + red[1] + red[2] + red[3];
  const float scale = rsqrtf(total * (1.f / 2048.f) + 1e-5f);
  BF8 o;
  #pragma unroll
  for (int j = 0; j < 8; ++j)
    o.h[j] = __float2bfloat16(t[j] * scale * norm_w[tid * 8 + j]);
  *(uint4*)(yr + tid * 8) = o.u;
}

// ---------------------------------------------------------------------------
extern "C" void kernel_launch(void* const* d_in, const int* in_sizes, int n_in,
                              void* d_out, int out_size, void* d_ws, size_t ws_size,
                              hipStream_t stream) {
  (void)in_sizes; (void)n_in; (void)out_size; (void)ws_size;
  const float* u          = (const float*)d_in[0];
  const float* in_proj_w  = (const float*)d_in[1];
  const float* conv_w     = (const float*)d_in[2];
  const float* conv_b     = (const float*)d_in[3];
  const float* dt_bias    = (const float*)d_in[4];
  const float* A_log      = (const float*)d_in[5];
  const float* Dp         = (const float*)d_in[6];
  const float* norm_w     = (const float*)d_in[7];
  const float* out_proj_w = (const float*)d_in[8];
  float* out = (float*)d_out;

  char* ws = (char*)d_ws;
  bf16*  u_bf   = (bf16*)ws;                           //  33,554,432
  bf16*  xpre   = (bf16*)(ws + 33554432);              //  76,546,048
  bf16*  xBCc   = (bf16*)(ws + 110100480);             //  75,497,472
  float* dtT    = (float*)(ws + 185597952);            //   2,097,152
  bf16*  W_xpre = (bf16*)(ws + 187695104);             //   4,784,128
  bf16*  W_z    = (bf16*)(ws + 192479232);             //   4,194,304
  bf16*  w_out  = (bf16*)(ws + 196673536);             //   4,194,304
  float* Atot   = (float*)(ws + 200867840);            //      32,768
  bf16*  states = (bf16*)(ws + 200900608);             //  33,554,432
  bf16*  ybuf   = xpre;                                // y ld 2048 (post-SSD)
  bf16*  zbuf   = xBCc;                                // z ld 2048 (post-SSD)

  // 0) conversions
  cvt_f32_bf16<<<dim3(8192), 256, 0, stream>>>(u, u_bf);
  cvt_f32_bf16<<<dim3(1168), 256, 0, stream>>>(in_proj_w + (size_t)2048*1024,
                                               W_xpre);   // 2336x1024
  cvt_f32_bf16<<<dim3(1024), 256, 0, stream>>>(in_proj_w, W_z);
  cvt_f32_bf16<<<dim3(1024), 256, 0, stream>>>(out_proj_w, w_out);
  // 1) GEMM-X: xpre = u_bf @ W_xpre^T  (N=2336, clamp B rows)
  gemm_bt_mfma<bf16, true><<<dim3(19, 128), 256, 0, stream>>>(
      u_bf, 1024, W_xpre, 1024, xpre, LDXP, 2336, 1024);
  // 2) dt softplus + Atot
  dtsp_atot_kernel<<<dim3(64, 4), 256, 0, stream>>>(xpre, dt_bias, A_log,
                                                    dtT, Atot);
  // 3) conv + silu
  conv_silu_kernel<<<dim3(9, 512, 4), 256, 0, stream>>>(xpre, conv_w, conv_b,
                                                        xBCc);
  // 4) SSD, one batch at a time (states buffer holds one batch)
  for (int b = 0; b < 4; ++b) {
    s1_localstate<<<dim3(64, 32), 256, 0, stream>>>(xBCc, dtT, A_log,
                                                    states, b);
    s2_scan<<<dim3(128), 256, 0, stream>>>(states, Atot, b);
    s3_output<<<dim3(64, 32), 256, 0, stream>>>(xBCc, dtT, A_log, Dp,
                                                states, ybuf, b);
  }
  // 5) GEMM-Z: z = u_bf @ W_z^T (over dead conv buffer)
  gemm_bt_mfma<bf16, false><<<dim3(16, 128), 256, 0, stream>>>(
      u_bf, 1024, W_z, 1024, zbuf, 2048, 2048, 1024);
  // 6) gate + rmsnorm (t over y)
  gate_rmsnorm_kernel<<<dim3(BL), 256, 0, stream>>>(ybuf, zbuf, norm_w);
  // 7) out_proj: out = t @ w_out^T
  gemm_bt_mfma<float, false><<<dim3(8, 128), 256, 0, stream>>>(
      ybuf, 2048, w_out, 2048, out, 1024, 1024, 2048);
}

// Round 6
// 602.349 us; speedup vs baseline: 6.8346x; 1.0459x over previous
//
#include <hip/hip_runtime.h>
#include <hip/hip_bf16.h>
#include <math.h>

// ---------------------------------------------------------------------------
// Mamba2 block forward. bf16 storage + MFMA everywhere, fp32 accumulate.
// b=4, L=4096, D_MODEL=1024, D_INNER=2048, D_STATE=128, N_HEADS=32, HEAD_DIM=64
//
// Memory plan (234,455,040 B total <= proven-safe 234.6 MB):
//   u_bf   bf16[16384][1024]  33,554,432  (input, bf16)
//   xpre   bf16[16384][2336]  76,546,048  (xBC_pre | dt_raw; y ld2048 after SSD)
//   xBCc   bf16[16384][2304]  75,497,472  (post conv+silu; z ld2048 after SSD)
//   dtT    f32 [4][32][4096]   2,097,152
//   W_xpre bf16[2336][1024]    4,784,128  (in_proj rows 2048..4384)
//   W_z    bf16[2048][1024]    4,194,304  (in_proj rows 0..2048)
//   w_out  bf16[1024][2048]    4,194,304
//   Atot   f32 [4][64][32]        32,768
//   states bf16[64][32][64][128] 33,554,432  (ONE batch; SSD runs 4 phases)
//
// R5: XCD-chunked block swizzle in GEMMs (FETCH 236MB was 8x A over-fetch),
//     S2 at 512 blocks (4x parallelism), S1/S3 grid transposed for L2 reuse.
// ---------------------------------------------------------------------------

#define BL    16384
#define NCONV 2304
#define LDXP  2336

typedef __hip_bfloat16 bf16;
typedef __attribute__((ext_vector_type(8))) short bf16x8_i;
typedef __attribute__((ext_vector_type(4))) float f32x4;

union BF8 { uint4 u; bf16 h[8]; };
union BF2 { uint u; bf16 h[2]; };

__device__ __forceinline__ void gload_lds16(const void* g, void* l) {
  __builtin_amdgcn_global_load_lds(
      (__attribute__((address_space(1))) void*)(uintptr_t)g,
      (__attribute__((address_space(3))) void*)(uint32_t)(uintptr_t)l,
      16, 0, 0);
}

// ---------------- bf16 MFMA GEMM:  C[m,n] = sum_k A[m,k] * B[n,k] ----------
// 128x128 tile, BK=32, 4 waves, 4x4 16x16x32 frags. XCD-chunked swizzle:
// requires (gridX*gridY) % 8 == 0 (true for all launches here).
template<typename TC, bool CLAMPB>
__global__ __launch_bounds__(256) void gemm_bt_mfma(
    const bf16* __restrict__ A, int lda,
    const bf16* __restrict__ B, int ldb,
    TC* __restrict__ C, int ldc, int N, int K)
{
  __shared__ __align__(16) bf16 As[128 * 32];
  __shared__ __align__(16) bf16 Bs[128 * 32];
  const int tid  = threadIdx.x;
  const int lane = tid & 63;
  const int wid  = tid >> 6;

  // XCD-chunked bijective swizzle: original dispatch id o runs on XCD o&7;
  // give XCD k the contiguous row-major tile range [k*q, (k+1)*q).
  const int gx  = gridDim.x;
  const int nwg = gx * gridDim.y;
  const int q   = nwg >> 3;
  int id = blockIdx.y * gx + blockIdx.x;
  id = (id & 7) * q + (id >> 3);
  const int bm = (id / gx) * 128;
  const int bn = (id % gx) * 128;

  const int wr = (wid >> 1) * 64;
  const int wc = (wid & 1) * 64;

  f32x4 acc[4][4] = {};

  int aoff[4], boff[4];
  #pragma unroll
  for (int i = 0; i < 4; ++i) {
    aoff[i] = (wr + i * 16 + (lane & 15)) * 32 + (lane >> 4) * 8;
    boff[i] = (wc + i * 16 + (lane & 15)) * 32 + (lane >> 4) * 8;
  }

  const int srow = tid >> 2, scol = (tid & 3) * 8;
  int brow0 = bn + srow, brow1 = bn + 64 + srow;
  if (CLAMPB) { brow0 = min(brow0, N - 1); brow1 = min(brow1, N - 1); }
  const bf16* pA0 = A + (size_t)(bm + srow) * lda + scol;
  const bf16* pA1 = pA0 + (size_t)lda * 64;
  const bf16* pB0 = B + (size_t)brow0 * ldb + scol;
  const bf16* pB1 = B + (size_t)brow1 * ldb + scol;
  bf16* lA0 = As + wid * 512;
  bf16* lA1 = As + 2048 + wid * 512;
  bf16* lB0 = Bs + wid * 512;
  bf16* lB1 = Bs + 2048 + wid * 512;

  for (int k0 = 0; k0 < K; k0 += 32) {
    gload_lds16(pA0, lA0);
    gload_lds16(pA1, lA1);
    gload_lds16(pB0, lB0);
    gload_lds16(pB1, lB1);
    pA0 += 32; pA1 += 32; pB0 += 32; pB1 += 32;
    __syncthreads();
    bf16x8_i af[4], bfr[4];
    #pragma unroll
    for (int i = 0; i < 4; ++i) {
      af[i]  = *(const bf16x8_i*)(As + aoff[i]);
      bfr[i] = *(const bf16x8_i*)(Bs + boff[i]);
    }
    #pragma unroll
    for (int i = 0; i < 4; ++i)
      #pragma unroll
      for (int j = 0; j < 4; ++j)
        acc[i][j] = __builtin_amdgcn_mfma_f32_16x16x32_bf16(
            af[i], bfr[j], acc[i][j], 0, 0, 0);
    __syncthreads();
  }

  const int cr = (lane >> 4) * 4;
  const int cc = lane & 15;
  #pragma unroll
  for (int i = 0; i < 4; ++i) {
    #pragma unroll
    for (int j = 0; j < 4; ++j) {
      const int n = bn + wc + j * 16 + cc;
      if (n < N) {
        #pragma unroll
        for (int r = 0; r < 4; ++r) {
          const int m = bm + wr + i * 16 + cr + r;
          if constexpr (sizeof(TC) == 2)
            ((bf16*)C)[(size_t)m * ldc + n] = __float2bfloat16(acc[i][j][r]);
          else
            ((float*)C)[(size_t)m * ldc + n] = acc[i][j][r];
        }
      }
    }
  }
}

// ---------------- conversion -----------------------------------------------
__global__ __launch_bounds__(256) void cvt_f32_bf16(
    const float* __restrict__ in, bf16* __restrict__ out)
{
  const size_t i = (size_t)(blockIdx.x * 256 + threadIdx.x) * 8;
  float4 a = *(const float4*)(in + i);
  float4 b = *(const float4*)(in + i + 4);
  BF8 o;
  o.h[0] = __float2bfloat16(a.x); o.h[1] = __float2bfloat16(a.y);
  o.h[2] = __float2bfloat16(a.z); o.h[3] = __float2bfloat16(a.w);
  o.h[4] = __float2bfloat16(b.x); o.h[5] = __float2bfloat16(b.y);
  o.h[6] = __float2bfloat16(b.z); o.h[7] = __float2bfloat16(b.w);
  *(uint4*)(out + i) = o.u;
}

// ---------------- dt softplus + per-chunk Atot -----------------------------
__global__ __launch_bounds__(256) void dtsp_atot_kernel(
    const bf16* __restrict__ xpre, const float* __restrict__ dt_bias,
    const float* __restrict__ A_log,
    float* __restrict__ dtT, float* __restrict__ Atot)
{
  const int c = blockIdx.x, b = blockIdx.y;
  const int tid = threadIdx.x;
  const int h = tid & 31, lg = tid >> 5;
  __shared__ float red[8][33];
  float s = 0.f, vals[8];
  const bf16* src = xpre + ((size_t)b * 4096 + c * 64 + lg * 8) * LDXP + 2304 + h;
  const float bias = dt_bias[h];
  #pragma unroll
  for (int k = 0; k < 8; ++k) {
    float v = __bfloat162float(src[(size_t)k * LDXP]) + bias;
    v = fmaxf(v, 0.f) + log1pf(expf(-fabsf(v)));
    vals[k] = v; s += v;
  }
  float* dp = dtT + ((size_t)(b * 32 + h)) * 4096 + c * 64 + lg * 8;
  #pragma unroll
  for (int k = 0; k < 8; ++k) dp[k] = vals[k];
  red[lg][h] = s;
  __syncthreads();
  if (tid < 32) {
    float t = 0.f;
    #pragma unroll
    for (int g = 0; g < 8; ++g) t += red[g][tid];
    Atot[((size_t)b * 64 + c) * 32 + tid] = -expf(A_log[tid]) * t;
  }
}

// ---------------- depthwise causal conv(4) + bias + silu -------------------
__global__ __launch_bounds__(256) void conv_silu_kernel(
    const bf16* __restrict__ xpre,
    const float* __restrict__ conv_w,
    const float* __restrict__ conv_b,
    bf16* __restrict__ xBC)
{
  const int ch = blockIdx.x * 256 + threadIdx.x;  // < 2304
  const int t0 = blockIdx.y * 8;
  const int bb = blockIdx.z;
  const float w0 = conv_w[ch*4+0], w1 = conv_w[ch*4+1];
  const float w2 = conv_w[ch*4+2], w3 = conv_w[ch*4+3];
  const float bias = conv_b[ch];
  const size_t rb = (size_t)bb * 4096;
  const bf16* src = xpre + ch;
  float v0 = (t0 >= 3) ? __bfloat162float(src[(rb + t0 - 3) * LDXP]) : 0.f;
  float v1 = (t0 >= 2) ? __bfloat162float(src[(rb + t0 - 2) * LDXP]) : 0.f;
  float v2 = (t0 >= 1) ? __bfloat162float(src[(rb + t0 - 1) * LDXP]) : 0.f;
  for (int t = t0; t < t0 + 8; ++t) {
    float v3 = __bfloat162float(src[(rb + t) * LDXP]);
    float o = bias + w0*v0 + w1*v1 + w2*v2 + w3*v3;
    o = o / (1.f + expf(-o));
    xBC[(rb + t) * NCONV + ch] = __float2bfloat16(o);
    v0 = v1; v1 = v2; v2 = v3;
  }
}

// swizzle helper: XOR the 8-block index of l by low bits of the row
__device__ __forceinline__ int swz8(int row) { return ((row >> 3) & 7) << 3; }

// ---------------- S1: chunk-local states via MFMA --------------------------
// grid (32 h, 64 c): concurrent blocks share one chunk's B reads in L2.
__global__ __launch_bounds__(256) void s1_localstate(
    const bf16* __restrict__ xBC, const float* __restrict__ dtT,
    const float* __restrict__ A_log, bf16* __restrict__ states, int b)
{
  const int hh = blockIdx.x, c = blockIdx.y;
  const int tid = threadIdx.x, lane = tid & 63, wid = tid >> 6;
  __shared__ bf16 BT[128 * 72];    // [n][l^swz]
  __shared__ bf16 xwT[64 * 72];    // [p][l^swz]
  __shared__ bf16 Sout[64 * 136];  // bounce for coalesced store
  const size_t r0 = (size_t)b * 4096 + (size_t)c * 64;

  BF8 regB[4], regx[2];
  #pragma unroll
  for (int k = 0; k < 4; ++k) {
    int id = tid + k * 256, l = id >> 4, n0 = (id & 15) * 8;
    regB[k].u = *(const uint4*)(xBC + (r0 + l) * NCONV + 2048 + n0);
  }
  #pragma unroll
  for (int k = 0; k < 2; ++k) {
    int id = tid + k * 256, l = id >> 3, p0 = (id & 7) * 8;
    regx[k].u = *(const uint4*)(xBC + (r0 + l) * NCONV + hh * 64 + p0);
  }

  // redundant per-wave cumsum: lane holds token l = lane
  float d = dtT[((size_t)(b * 32 + hh)) * 4096 + c * 64 + lane];
  float Ah = -expf(A_log[hh]);
  float v = Ah * d;
  #pragma unroll
  for (int off = 1; off < 64; off <<= 1) {
    float up = __shfl_up(v, off, 64);
    if (lane >= off) v += up;
  }
  const float At = __shfl(v, 63, 64);
  const float w = d * __expf(At - v);

  #pragma unroll
  for (int k = 0; k < 4; ++k) {
    int id = tid + k * 256, l = id >> 4, n0 = (id & 15) * 8;
    #pragma unroll
    for (int j = 0; j < 8; ++j) {
      int n = n0 + j;
      BT[n * 72 + (l ^ swz8(n))] = regB[k].h[j];
    }
  }
  #pragma unroll
  for (int k = 0; k < 2; ++k) {
    int id = tid + k * 256, l = id >> 3, p0 = (id & 7) * 8;
    float wv = __shfl(w, l, 64);
    #pragma unroll
    for (int j = 0; j < 8; ++j) {
      int p = p0 + j;
      xwT[p * 72 + (l ^ swz8(p))] =
          __float2bfloat16(__bfloat162float(regx[k].h[j]) * wv);
    }
  }
  __syncthreads();

  // MFMA: M=p(64), N=n(128), K=l(64)
  const int wr = (wid & 1) * 32;   // p
  const int wc = (wid >> 1) * 64;  // n
  f32x4 acc[2][4] = {};
  #pragma unroll
  for (int ks = 0; ks < 2; ++ks) {
    const int k0 = ks * 32 + (lane >> 4) * 8;
    bf16x8_i a[2], bb[4];
    #pragma unroll
    for (int i = 0; i < 2; ++i) {
      int p = wr + i * 16 + (lane & 15);
      a[i] = *(const bf16x8_i*)(xwT + p * 72 + (k0 ^ swz8(p)));
    }
    #pragma unroll
    for (int j = 0; j < 4; ++j) {
      int n = wc + j * 16 + (lane & 15);
      bb[j] = *(const bf16x8_i*)(BT + n * 72 + (k0 ^ swz8(n)));
    }
    #pragma unroll
    for (int i = 0; i < 2; ++i)
      #pragma unroll
      for (int j = 0; j < 4; ++j)
        acc[i][j] = __builtin_amdgcn_mfma_f32_16x16x32_bf16(
            a[i], bb[j], acc[i][j], 0, 0, 0);
  }

  const int cr = (lane >> 4) * 4, cn = lane & 15;
  #pragma unroll
  for (int i = 0; i < 2; ++i)
    #pragma unroll
    for (int j = 0; j < 4; ++j)
      #pragma unroll
      for (int r = 0; r < 4; ++r)
        Sout[(wr + i * 16 + cr + r) * 136 + (wc + j * 16 + cn)] =
            __float2bfloat16(acc[i][j][r]);
  __syncthreads();
  bf16* sb = states + ((size_t)c * 32 + hh) * 8192;
  #pragma unroll
  for (int k = 0; k < 4; ++k) {
    int id = tid + k * 256, p = id >> 4, n0 = (id & 15) * 8;
    *(uint4*)(sb + p * 128 + n0) = *(const uint4*)(Sout + p * 136 + n0);
  }
}

// ---------------- S2: in-place scan over chunks (4-deep pipelined) ---------
// grid 512 blocks x 256 thr: block -> (h, p-quad), thread -> (p, n-pair).
__global__ __launch_bounds__(256) void s2_scan(
    bf16* __restrict__ states, const float* __restrict__ Atot, int b)
{
  const int h  = blockIdx.x >> 4;
  const int p  = ((blockIdx.x & 15) << 2) | (threadIdx.x >> 6);
  const int n0 = (threadIdx.x & 63) * 2;
  __shared__ float ec[64];
  if (threadIdx.x < 64)
    ec[threadIdx.x] = expf(Atot[((size_t)b * 64 + threadIdx.x) * 32 + h]);
  __syncthreads();
  bf16* ptr = states + ((size_t)h * 64 + p) * 128 + n0;
  const size_t cs = (size_t)32 * 8192;   // chunk stride
  float ca = 0.f, cb = 0.f;              // carry pair
  BF2 g0, g1, g2, g3, q0, q1, q2, q3;
  g0.u = *(const uint*)(ptr + 0 * cs);
  g1.u = *(const uint*)(ptr + 1 * cs);
  g2.u = *(const uint*)(ptr + 2 * cs);
  g3.u = *(const uint*)(ptr + 3 * cs);
  for (int g = 0; g < 16; ++g) {
    const int c0 = g * 4;
    if (g < 15) {
      q0.u = *(const uint*)(ptr + (c0 + 4) * cs);
      q1.u = *(const uint*)(ptr + (c0 + 5) * cs);
      q2.u = *(const uint*)(ptr + (c0 + 6) * cs);
      q3.u = *(const uint*)(ptr + (c0 + 7) * cs);
    }
    BF2 o0, o1, o2, o3;
    const float e0 = ec[c0], e1 = ec[c0+1], e2 = ec[c0+2], e3 = ec[c0+3];
    o0.h[0] = __float2bfloat16(ca); o0.h[1] = __float2bfloat16(cb);
    ca = fmaf(e0, ca, __bfloat162float(g0.h[0]));
    cb = fmaf(e0, cb, __bfloat162float(g0.h[1]));
    o1.h[0] = __float2bfloat16(ca); o1.h[1] = __float2bfloat16(cb);
    ca = fmaf(e1, ca, __bfloat162float(g1.h[0]));
    cb = fmaf(e1, cb, __bfloat162float(g1.h[1]));
    o2.h[0] = __float2bfloat16(ca); o2.h[1] = __float2bfloat16(cb);
    ca = fmaf(e2, ca, __bfloat162float(g2.h[0]));
    cb = fmaf(e2, cb, __bfloat162float(g2.h[1]));
    o3.h[0] = __float2bfloat16(ca); o3.h[1] = __float2bfloat16(cb);
    ca = fmaf(e3, ca, __bfloat162float(g3.h[0]));
    cb = fmaf(e3, cb, __bfloat162float(g3.h[1]));
    *(uint*)(ptr + (c0 + 0) * cs) = o0.u;
    *(uint*)(ptr + (c0 + 1) * cs) = o1.u;
    *(uint*)(ptr + (c0 + 2) * cs) = o2.u;
    *(uint*)(ptr + (c0 + 3) * cs) = o3.u;
    g0 = q0; g1 = q1; g2 = q2; g3 = q3;
  }
}

// ---------------- S3: chunk outputs via MFMA -------------------------------
// grid (32 h, 64 c), one batch b. Y written packed ld 2048.
__global__ __launch_bounds__(256) void s3_output(
    const bf16* __restrict__ xBC, const float* __restrict__ dtT,
    const float* __restrict__ A_log, const float* __restrict__ Dp,
    const bf16* __restrict__ states, bf16* __restrict__ Y, int b)
{
  const int hh = blockIdx.x, c = blockIdx.y;
  const int tid = threadIdx.x, lane = tid & 63, wid = tid >> 6;
  __shared__ bf16 Cc[64 * 136];   // [l][n]
  __shared__ bf16 Bc[64 * 136];   // [s][n]; reused as Yb
  __shared__ bf16 Sin[64 * 136];  // [p][n]
  __shared__ bf16 xT[64 * 72];    // [p][l^swz]
  __shared__ bf16 scb[64 * 72];   // [l][s]
  __shared__ float Ac[64], dts[64];
  const size_t r0 = (size_t)b * 4096 + (size_t)c * 64;

  if (tid < 64) {
    float d = dtT[((size_t)(b * 32 + hh)) * 4096 + c * 64 + tid];
    float Ah = -expf(A_log[hh]);
    float v = Ah * d;
    #pragma unroll
    for (int off = 1; off < 64; off <<= 1) {
      float up = __shfl_up(v, off, 64);
      if (tid >= off) v += up;
    }
    Ac[tid] = v; dts[tid] = d;
  }

  #pragma unroll
  for (int k = 0; k < 4; ++k) {
    int id = tid + k * 256, l = id >> 4, n0 = (id & 15) * 8;
    BF8 bv; bv.u = *(const uint4*)(xBC + (r0 + l) * NCONV + 2048 + n0);
    BF8 cv; cv.u = *(const uint4*)(xBC + (r0 + l) * NCONV + 2176 + n0);
    *(uint4*)(Bc + l * 136 + n0) = bv.u;
    *(uint4*)(Cc + l * 136 + n0) = cv.u;
  }
  const bf16* sb = states + ((size_t)c * 32 + hh) * 8192;
  #pragma unroll
  for (int k = 0; k < 4; ++k) {
    int id = tid + k * 256, p = id >> 4, n0 = (id & 15) * 8;
    *(uint4*)(Sin + p * 136 + n0) = *(const uint4*)(sb + p * 128 + n0);
  }
  #pragma unroll
  for (int k = 0; k < 2; ++k) {
    int id = tid + k * 256, l = id >> 3, p0 = (id & 7) * 8;
    BF8 v; v.u = *(const uint4*)(xBC + (r0 + l) * NCONV + hh * 64 + p0);
    #pragma unroll
    for (int j = 0; j < 8; ++j) {
      int p = p0 + j;
      xT[p * 72 + (l ^ swz8(p))] = v.h[j];
    }
  }
  __syncthreads();

  // scores: M=l, N=s, K=n(128); A-frags (C rows) cached for Y_off reuse
  const int wr  = (wid & 1) * 32;   // l
  const int wcs = (wid >> 1) * 32;  // s / p
  f32x4 as[2][2] = {};
  bf16x8_i afrag[2][4];
  #pragma unroll
  for (int ks = 0; ks < 4; ++ks) {
    const int k0 = ks * 32 + (lane >> 4) * 8;
    #pragma unroll
    for (int i = 0; i < 2; ++i)
      afrag[i][ks] =
          *(const bf16x8_i*)(Cc + (wr + i * 16 + (lane & 15)) * 136 + k0);
    #pragma unroll
    for (int j = 0; j < 2; ++j) {
      bf16x8_i bfr =
          *(const bf16x8_i*)(Bc + (wcs + j * 16 + (lane & 15)) * 136 + k0);
      #pragma unroll
      for (int i = 0; i < 2; ++i)
        as[i][j] = __builtin_amdgcn_mfma_f32_16x16x32_bf16(
            afrag[i][ks], bfr, as[i][j], 0, 0, 0);
    }
  }
  const int cr = (lane >> 4) * 4, cc = lane & 15;
  #pragma unroll
  for (int i = 0; i < 2; ++i) {
    #pragma unroll
    for (int r = 0; r < 4; ++r) {
      const int l = wr + i * 16 + cr + r;
      const float acl = Ac[l];
      #pragma unroll
      for (int j = 0; j < 2; ++j) {
        const int s = wcs + j * 16 + cc;
        float val = (s <= l) ? as[i][j][r] * __expf(acl - Ac[s]) * dts[s] : 0.f;
        scb[l * 72 + s] = __float2bfloat16(val);
      }
    }
  }
  __syncthreads();

  // Y_off = C.S_in^T (K=128) scaled by dko_l, += scores.x (K=64)
  f32x4 ay[2][2] = {};
  #pragma unroll
  for (int ks = 0; ks < 4; ++ks) {
    const int k0 = ks * 32 + (lane >> 4) * 8;
    #pragma unroll
    for (int j = 0; j < 2; ++j) {
      bf16x8_i bfr =
          *(const bf16x8_i*)(Sin + (wcs + j * 16 + (lane & 15)) * 136 + k0);
      #pragma unroll
      for (int i = 0; i < 2; ++i)
        ay[i][j] = __builtin_amdgcn_mfma_f32_16x16x32_bf16(
            afrag[i][ks], bfr, ay[i][j], 0, 0, 0);
    }
  }
  #pragma unroll
  for (int i = 0; i < 2; ++i)
    #pragma unroll
    for (int r = 0; r < 4; ++r) {
      const float dk = __expf(Ac[wr + i * 16 + cr + r]);
      #pragma unroll
      for (int j = 0; j < 2; ++j) ay[i][j][r] *= dk;
    }
  #pragma unroll
  for (int ks = 0; ks < 2; ++ks) {
    const int k0 = ks * 32 + (lane >> 4) * 8;
    bf16x8_i a2[2], b2[2];
    #pragma unroll
    for (int i = 0; i < 2; ++i)
      a2[i] = *(const bf16x8_i*)(scb + (wr + i * 16 + (lane & 15)) * 72 + k0);
    #pragma unroll
    for (int j = 0; j < 2; ++j) {
      int p = wcs + j * 16 + (lane & 15);
      b2[j] = *(const bf16x8_i*)(xT + p * 72 + (k0 ^ swz8(p)));
    }
    #pragma unroll
    for (int i = 0; i < 2; ++i)
      #pragma unroll
      for (int j = 0; j < 2; ++j)
        ay[i][j] = __builtin_amdgcn_mfma_f32_16x16x32_bf16(
            a2[i], b2[j], ay[i][j], 0, 0, 0);
  }
  const float Dh = Dp[hh];
  bf16* Yb = Bc;
  #pragma unroll
  for (int i = 0; i < 2; ++i)
    #pragma unroll
    for (int r = 0; r < 4; ++r) {
      const int l = wr + i * 16 + cr + r;
      #pragma unroll
      for (int j = 0; j < 2; ++j) {
        const int p = wcs + j * 16 + cc;
        float xv = __bfloat162float(xT[p * 72 + (l ^ swz8(p))]);
        Yb[l * 136 + p] = __float2bfloat16(ay[i][j][r] + Dh * xv);
      }
    }
  __syncthreads();
  #pragma unroll
  for (int k = 0; k < 2; ++k) {
    int id = tid + k * 256, l = id >> 3, p0 = (id & 7) * 8;
    *(uint4*)(Y + (r0 + l) * 2048 + hh * 64 + p0) =
        *(const uint4*)(Yb + l * 136 + p0);
  }
}

// ---------------- t = rmsnorm(y * silu(z)) * norm_w  (in place over y) -----
__global__ __launch_bounds__(256) void gate_rmsnorm_kernel(
    bf16* __restrict__ y, const bf16* __restrict__ z,
    const float* __restrict__ norm_w)
{
  const size_t row = blockIdx.x;
  const int tid = threadIdx.x;
  __shared__ float red[4];
  const bf16* zr = z + row * 2048;
  bf16* yr = y + row * 2048;
  BF8 zv, yv;
  zv.u = *(const uint4*)(zr + tid * 8);
  yv.u = *(const uint4*)(yr + tid * 8);
  float t[8];
  float local = 0.f;
  #pragma unroll
  for (int j = 0; j < 8; ++j) {
    float zz = __bfloat162float(zv.h[j]);
    float yy = __bfloat162float(yv.h[j]);
    float tv = yy * (zz / (1.f + expf(-zz)));
    t[j] = tv;
    local += tv * tv;
  }
  #pragma unroll
  for (int off = 32; off; off >>= 1) local += __shfl_down(local, off, 64);
  if ((tid & 63) == 0) red[tid >> 6] = local;
  __syncthreads();
  const float total = red[0] + red[1] + red[2] + red[3];
  const float scale = rsqrtf(total * (1.f / 2048.f) + 1e-5f);
  BF8 o;
  #pragma unroll
  for (int j = 0; j < 8; ++j)
    o.h[j] = __float2bfloat16(t[j] * scale * norm_w[tid * 8 + j]);
  *(uint4*)(yr + tid * 8) = o.u;
}

// ---------------------------------------------------------------------------
extern "C" void kernel_launch(void* const* d_in, const int* in_sizes, int n_in,
                              void* d_out, int out_size, void* d_ws, size_t ws_size,
                              hipStream_t stream) {
  (void)in_sizes; (void)n_in; (void)out_size; (void)ws_size;
  const float* u          = (const float*)d_in[0];
  const float* in_proj_w  = (const float*)d_in[1];
  const float* conv_w     = (const float*)d_in[2];
  const float* conv_b     = (const float*)d_in[3];
  const float* dt_bias    = (const float*)d_in[4];
  const float* A_log      = (const float*)d_in[5];
  const float* Dp         = (const float*)d_in[6];
  const float* norm_w     = (const float*)d_in[7];
  const float* out_proj_w = (const float*)d_in[8];
  float* out = (float*)d_out;

  char* ws = (char*)d_ws;
  bf16*  u_bf   = (bf16*)ws;                           //  33,554,432
  bf16*  xpre   = (bf16*)(ws + 33554432);              //  76,546,048
  bf16*  xBCc   = (bf16*)(ws + 110100480);             //  75,497,472
  float* dtT    = (float*)(ws + 185597952);            //   2,097,152
  bf16*  W_xpre = (bf16*)(ws + 187695104);             //   4,784,128
  bf16*  W_z    = (bf16*)(ws + 192479232);             //   4,194,304
  bf16*  w_out  = (bf16*)(ws + 196673536);             //   4,194,304
  float* Atot   = (float*)(ws + 200867840);            //      32,768
  bf16*  states = (bf16*)(ws + 200900608);             //  33,554,432
  bf16*  ybuf   = xpre;                                // y ld 2048 (post-SSD)
  bf16*  zbuf   = xBCc;                                // z ld 2048 (post-SSD)

  // 0) conversions
  cvt_f32_bf16<<<dim3(8192), 256, 0, stream>>>(u, u_bf);
  cvt_f32_bf16<<<dim3(1168), 256, 0, stream>>>(in_proj_w + (size_t)2048*1024,
                                               W_xpre);   // 2336x1024
  cvt_f32_bf16<<<dim3(1024), 256, 0, stream>>>(in_proj_w, W_z);
  cvt_f32_bf16<<<dim3(1024), 256, 0, stream>>>(out_proj_w, w_out);
  // 1) GEMM-X: xpre = u_bf @ W_xpre^T  (N=2336, clamp B rows)
  gemm_bt_mfma<bf16, true><<<dim3(19, 128), 256, 0, stream>>>(
      u_bf, 1024, W_xpre, 1024, xpre, LDXP, 2336, 1024);
  // 2) dt softplus + Atot
  dtsp_atot_kernel<<<dim3(64, 4), 256, 0, stream>>>(xpre, dt_bias, A_log,
                                                    dtT, Atot);
  // 3) conv + silu
  conv_silu_kernel<<<dim3(9, 512, 4), 256, 0, stream>>>(xpre, conv_w, conv_b,
                                                        xBCc);
  // 4) SSD, one batch at a time (states buffer holds one batch)
  for (int b = 0; b < 4; ++b) {
    s1_localstate<<<dim3(32, 64), 256, 0, stream>>>(xBCc, dtT, A_log,
                                                    states, b);
    s2_scan<<<dim3(512), 256, 0, stream>>>(states, Atot, b);
    s3_output<<<dim3(32, 64), 256, 0, stream>>>(xBCc, dtT, A_log, Dp,
                                                states, ybuf, b);
  }
  // 5) GEMM-Z: z = u_bf @ W_z^T (over dead conv buffer)
  gemm_bt_mfma<bf16, false><<<dim3(16, 128), 256, 0, stream>>>(
      u_bf, 1024, W_z, 1024, zbuf, 2048, 2048, 1024);
  // 6) gate + rmsnorm (t over y)
  gate_rmsnorm_kernel<<<dim3(BL), 256, 0, stream>>>(ybuf, zbuf, norm_w);
  // 7) out_proj: out = t @ w_out^T
  gemm_bt_mfma<float, false><<<dim3(8, 128), 256, 0, stream>>>(
      ybuf, 2048, w_out, 2048, out, 1024, 1024, 2048);
}

// Round 7
// 516.628 us; speedup vs baseline: 7.9686x; 1.1659x over previous
//
#include <hip/hip_runtime.h>
#include <hip/hip_bf16.h>
#include <math.h>

// ---------------------------------------------------------------------------
// Mamba2 block forward. bf16 storage + MFMA everywhere, fp32 accumulate.
// b=4, L=4096, D_MODEL=1024, D_INNER=2048, D_STATE=128, N_HEADS=32, HEAD_DIM=64
//
// Memory plan (234,455,040 B <= proven-safe 234.6 MB): see R4/R5 comments.
// R7: GEMM rewritten as counted-vmcnt pipeline: BK=64, double-buffered LDS
//     (64KB), raw s_barrier + s_waitcnt vmcnt(8) (loads stay in flight across
//     barriers), derived XOR swizzle (row bits 2-3 -> elem bits 4-5) applied
//     to ds_read addr + inverse-permuted global staging source (linear
//     global_load_lds dest), setprio around MFMA cluster.
// ---------------------------------------------------------------------------

#define BL    16384
#define NCONV 2304
#define LDXP  2336

typedef __hip_bfloat16 bf16;
typedef __attribute__((ext_vector_type(8))) short bf16x8_i;
typedef __attribute__((ext_vector_type(4))) float f32x4;

union BF8 { uint4 u; bf16 h[8]; };
union BF2 { uint u; bf16 h[2]; };

__device__ __forceinline__ void gload_lds16(const void* g, void* l) {
  __builtin_amdgcn_global_load_lds(
      (__attribute__((address_space(1))) void*)(uintptr_t)g,
      (__attribute__((address_space(3))) void*)(uint32_t)(uintptr_t)l,
      16, 0, 0);
}

// ---------------- bf16 MFMA GEMM:  C[m,n] = sum_k A[m,k] * B[n,k] ----------
// 128x128 tile, BK=64, 4 waves, 4x4 16x16x32 frags x 2 k-halves.
// Double-buffered LDS + counted vmcnt: tile t+1 staged while computing t.
template<typename TC, bool CLAMPB>
__global__ __launch_bounds__(256) void gemm_bt_mfma(
    const bf16* __restrict__ A, int lda,
    const bf16* __restrict__ B, int ldb,
    TC* __restrict__ C, int ldc, int N, int K)
{
  __shared__ __align__(16) bf16 As2[2][128 * 64];   // 32 KB
  __shared__ __align__(16) bf16 Bs2[2][128 * 64];   // 32 KB
  const int tid  = threadIdx.x;
  const int lane = tid & 63;
  const int wid  = tid >> 6;

  // XCD-chunked bijective swizzle (requires nwg % 8 == 0)
  const int gx  = gridDim.x;
  const int nwg = gx * gridDim.y;
  const int q   = nwg >> 3;
  int id = blockIdx.y * gx + blockIdx.x;
  id = (id & 7) * q + (id >> 3);
  const int bm = (id / gx) * 128;
  const int bn = (id % gx) * 128;

  const int wr = (wid >> 1) * 64;
  const int wc = (wid & 1) * 64;

  f32x4 acc[4][4] = {};

  // LDS read offsets with swizzle: elem col c0 ^= ((row>>2)&3)<<4
  int aoff[4][2], boff[4][2];
  #pragma unroll
  for (int i = 0; i < 4; ++i) {
    const int ar = wr + i * 16 + (lane & 15);
    const int br = wc + i * 16 + (lane & 15);
    const int asw = ((ar >> 2) & 3) << 4;
    const int bsw = ((br >> 2) & 3) << 4;
    #pragma unroll
    for (int ks = 0; ks < 2; ++ks) {
      const int c0 = ks * 32 + (lane >> 4) * 8;
      aoff[i][ks] = ar * 64 + (c0 ^ asw);
      boff[i][ks] = br * 64 + (c0 ^ bsw);
    }
  }

  // staging map: issue i covers LDS rows i*32 + (tid>>3), 8-elem block tid&7.
  // Source col block inverse-swizzled so linear LDS holds the swizzled tile.
  const int srow = tid >> 3;
  const int sj   = tid & 7;
  const bf16* pA[4];
  const bf16* pB[4];
  #pragma unroll
  for (int i = 0; i < 4; ++i) {
    const int r  = i * 32 + srow;
    const int js = sj ^ (((r >> 2) & 3) << 1);
    int brow = bn + r;
    if (CLAMPB) brow = min(brow, N - 1);
    pA[i] = A + (size_t)(bm + r) * lda + js * 8;
    pB[i] = B + (size_t)brow * ldb + js * 8;
  }

  const int NT = K >> 6;
  // prologue: stage tile 0 into buf 0
  #pragma unroll
  for (int i = 0; i < 4; ++i) {
    gload_lds16(pA[i], &As2[0][0] + i * 2048 + wid * 512);
    gload_lds16(pB[i], &Bs2[0][0] + i * 2048 + wid * 512);
    pA[i] += 64; pB[i] += 64;
  }

  for (int t = 0; t < NT; ++t) {
    const int cur = t & 1;
    if (t + 1 < NT) {
      bf16* dA = &As2[cur ^ 1][0];
      bf16* dB = &Bs2[cur ^ 1][0];
      #pragma unroll
      for (int i = 0; i < 4; ++i) {
        gload_lds16(pA[i], dA + i * 2048 + wid * 512);
        gload_lds16(pB[i], dB + i * 2048 + wid * 512);
        pA[i] += 64; pB[i] += 64;
      }
      asm volatile("s_waitcnt vmcnt(8)" ::: "memory");
    } else {
      asm volatile("s_waitcnt vmcnt(0)" ::: "memory");
    }
    __builtin_amdgcn_sched_barrier(0);
    __builtin_amdgcn_s_barrier();      // all waves' tile-t staging visible
    const bf16* Ab = &As2[cur][0];
    const bf16* Bb = &Bs2[cur][0];
    __builtin_amdgcn_s_setprio(1);
    #pragma unroll
    for (int ks = 0; ks < 2; ++ks) {
      bf16x8_i af[4], bfr[4];
      #pragma unroll
      for (int i = 0; i < 4; ++i) {
        af[i]  = *(const bf16x8_i*)(Ab + aoff[i][ks]);
        bfr[i] = *(const bf16x8_i*)(Bb + boff[i][ks]);
      }
      #pragma unroll
      for (int i = 0; i < 4; ++i)
        #pragma unroll
        for (int j = 0; j < 4; ++j)
          acc[i][j] = __builtin_amdgcn_mfma_f32_16x16x32_bf16(
              af[i], bfr[j], acc[i][j], 0, 0, 0);
    }
    __builtin_amdgcn_s_setprio(0);
    __builtin_amdgcn_s_barrier();      // keep waves off next staging of buf
  }

  const int cr = (lane >> 4) * 4;
  const int cc = lane & 15;
  #pragma unroll
  for (int i = 0; i < 4; ++i) {
    #pragma unroll
    for (int j = 0; j < 4; ++j) {
      const int n = bn + wc + j * 16 + cc;
      if (n < N) {
        #pragma unroll
        for (int r = 0; r < 4; ++r) {
          const int m = bm + wr + i * 16 + cr + r;
          if constexpr (sizeof(TC) == 2)
            ((bf16*)C)[(size_t)m * ldc + n] = __float2bfloat16(acc[i][j][r]);
          else
            ((float*)C)[(size_t)m * ldc + n] = acc[i][j][r];
        }
      }
    }
  }
}

// ---------------- conversion -----------------------------------------------
__global__ __launch_bounds__(256) void cvt_f32_bf16(
    const float* __restrict__ in, bf16* __restrict__ out)
{
  const size_t i = (size_t)(blockIdx.x * 256 + threadIdx.x) * 8;
  float4 a = *(const float4*)(in + i);
  float4 b = *(const float4*)(in + i + 4);
  BF8 o;
  o.h[0] = __float2bfloat16(a.x); o.h[1] = __float2bfloat16(a.y);
  o.h[2] = __float2bfloat16(a.z); o.h[3] = __float2bfloat16(a.w);
  o.h[4] = __float2bfloat16(b.x); o.h[5] = __float2bfloat16(b.y);
  o.h[6] = __float2bfloat16(b.z); o.h[7] = __float2bfloat16(b.w);
  *(uint4*)(out + i) = o.u;
}

// ---------------- dt softplus + per-chunk Atot -----------------------------
__global__ __launch_bounds__(256) void dtsp_atot_kernel(
    const bf16* __restrict__ xpre, const float* __restrict__ dt_bias,
    const float* __restrict__ A_log,
    float* __restrict__ dtT, float* __restrict__ Atot)
{
  const int c = blockIdx.x, b = blockIdx.y;
  const int tid = threadIdx.x;
  const int h = tid & 31, lg = tid >> 5;
  __shared__ float red[8][33];
  float s = 0.f, vals[8];
  const bf16* src = xpre + ((size_t)b * 4096 + c * 64 + lg * 8) * LDXP + 2304 + h;
  const float bias = dt_bias[h];
  #pragma unroll
  for (int k = 0; k < 8; ++k) {
    float v = __bfloat162float(src[(size_t)k * LDXP]) + bias;
    v = fmaxf(v, 0.f) + log1pf(expf(-fabsf(v)));
    vals[k] = v; s += v;
  }
  float* dp = dtT + ((size_t)(b * 32 + h)) * 4096 + c * 64 + lg * 8;
  #pragma unroll
  for (int k = 0; k < 8; ++k) dp[k] = vals[k];
  red[lg][h] = s;
  __syncthreads();
  if (tid < 32) {
    float t = 0.f;
    #pragma unroll
    for (int g = 0; g < 8; ++g) t += red[g][tid];
    Atot[((size_t)b * 64 + c) * 32 + tid] = -expf(A_log[tid]) * t;
  }
}

// ---------------- depthwise causal conv(4) + bias + silu -------------------
__global__ __launch_bounds__(256) void conv_silu_kernel(
    const bf16* __restrict__ xpre,
    const float* __restrict__ conv_w,
    const float* __restrict__ conv_b,
    bf16* __restrict__ xBC)
{
  const int ch = blockIdx.x * 256 + threadIdx.x;  // < 2304
  const int t0 = blockIdx.y * 8;
  const int bb = blockIdx.z;
  const float w0 = conv_w[ch*4+0], w1 = conv_w[ch*4+1];
  const float w2 = conv_w[ch*4+2], w3 = conv_w[ch*4+3];
  const float bias = conv_b[ch];
  const size_t rb = (size_t)bb * 4096;
  const bf16* src = xpre + ch;
  float v0 = (t0 >= 3) ? __bfloat162float(src[(rb + t0 - 3) * LDXP]) : 0.f;
  float v1 = (t0 >= 2) ? __bfloat162float(src[(rb + t0 - 2) * LDXP]) : 0.f;
  float v2 = (t0 >= 1) ? __bfloat162float(src[(rb + t0 - 1) * LDXP]) : 0.f;
  for (int t = t0; t < t0 + 8; ++t) {
    float v3 = __bfloat162float(src[(rb + t) * LDXP]);
    float o = bias + w0*v0 + w1*v1 + w2*v2 + w3*v3;
    o = o / (1.f + expf(-o));
    xBC[(rb + t) * NCONV + ch] = __float2bfloat16(o);
    v0 = v1; v1 = v2; v2 = v3;
  }
}

// swizzle helper: XOR the 8-block index of l by low bits of the row
__device__ __forceinline__ int swz8(int row) { return ((row >> 3) & 7) << 3; }

// ---------------- S1: chunk-local states via MFMA --------------------------
// grid (32 h, 64 c): concurrent blocks share one chunk's B reads in L2.
__global__ __launch_bounds__(256) void s1_localstate(
    const bf16* __restrict__ xBC, const float* __restrict__ dtT,
    const float* __restrict__ A_log, bf16* __restrict__ states, int b)
{
  const int hh = blockIdx.x, c = blockIdx.y;
  const int tid = threadIdx.x, lane = tid & 63, wid = tid >> 6;
  __shared__ bf16 BT[128 * 72];    // [n][l^swz]
  __shared__ bf16 xwT[64 * 72];    // [p][l^swz]
  __shared__ bf16 Sout[64 * 136];  // bounce for coalesced store
  const size_t r0 = (size_t)b * 4096 + (size_t)c * 64;

  BF8 regB[4], regx[2];
  #pragma unroll
  for (int k = 0; k < 4; ++k) {
    int id = tid + k * 256, l = id >> 4, n0 = (id & 15) * 8;
    regB[k].u = *(const uint4*)(xBC + (r0 + l) * NCONV + 2048 + n0);
  }
  #pragma unroll
  for (int k = 0; k < 2; ++k) {
    int id = tid + k * 256, l = id >> 3, p0 = (id & 7) * 8;
    regx[k].u = *(const uint4*)(xBC + (r0 + l) * NCONV + hh * 64 + p0);
  }

  // redundant per-wave cumsum: lane holds token l = lane
  float d = dtT[((size_t)(b * 32 + hh)) * 4096 + c * 64 + lane];
  float Ah = -expf(A_log[hh]);
  float v = Ah * d;
  #pragma unroll
  for (int off = 1; off < 64; off <<= 1) {
    float up = __shfl_up(v, off, 64);
    if (lane >= off) v += up;
  }
  const float At = __shfl(v, 63, 64);
  const float w = d * __expf(At - v);

  #pragma unroll
  for (int k = 0; k < 4; ++k) {
    int id = tid + k * 256, l = id >> 4, n0 = (id & 15) * 8;
    #pragma unroll
    for (int j = 0; j < 8; ++j) {
      int n = n0 + j;
      BT[n * 72 + (l ^ swz8(n))] = regB[k].h[j];
    }
  }
  #pragma unroll
  for (int k = 0; k < 2; ++k) {
    int id = tid + k * 256, l = id >> 3, p0 = (id & 7) * 8;
    float wv = __shfl(w, l, 64);
    #pragma unroll
    for (int j = 0; j < 8; ++j) {
      int p = p0 + j;
      xwT[p * 72 + (l ^ swz8(p))] =
          __float2bfloat16(__bfloat162float(regx[k].h[j]) * wv);
    }
  }
  __syncthreads();

  // MFMA: M=p(64), N=n(128), K=l(64)
  const int wr = (wid & 1) * 32;   // p
  const int wc = (wid >> 1) * 64;  // n
  f32x4 acc[2][4] = {};
  #pragma unroll
  for (int ks = 0; ks < 2; ++ks) {
    const int k0 = ks * 32 + (lane >> 4) * 8;
    bf16x8_i a[2], bb[4];
    #pragma unroll
    for (int i = 0; i < 2; ++i) {
      int p = wr + i * 16 + (lane & 15);
      a[i] = *(const bf16x8_i*)(xwT + p * 72 + (k0 ^ swz8(p)));
    }
    #pragma unroll
    for (int j = 0; j < 4; ++j) {
      int n = wc + j * 16 + (lane & 15);
      bb[j] = *(const bf16x8_i*)(BT + n * 72 + (k0 ^ swz8(n)));
    }
    #pragma unroll
    for (int i = 0; i < 2; ++i)
      #pragma unroll
      for (int j = 0; j < 4; ++j)
        acc[i][j] = __builtin_amdgcn_mfma_f32_16x16x32_bf16(
            a[i], bb[j], acc[i][j], 0, 0, 0);
  }

  const int cr = (lane >> 4) * 4, cn = lane & 15;
  #pragma unroll
  for (int i = 0; i < 2; ++i)
    #pragma unroll
    for (int j = 0; j < 4; ++j)
      #pragma unroll
      for (int r = 0; r < 4; ++r)
        Sout[(wr + i * 16 + cr + r) * 136 + (wc + j * 16 + cn)] =
            __float2bfloat16(acc[i][j][r]);
  __syncthreads();
  bf16* sb = states + ((size_t)c * 32 + hh) * 8192;
  #pragma unroll
  for (int k = 0; k < 4; ++k) {
    int id = tid + k * 256, p = id >> 4, n0 = (id & 15) * 8;
    *(uint4*)(sb + p * 128 + n0) = *(const uint4*)(Sout + p * 136 + n0);
  }
}

// ---------------- S2: in-place scan over chunks (4-deep pipelined) ---------
// grid 512 blocks x 256 thr: block -> (h, p-quad), thread -> (p, n-pair).
__global__ __launch_bounds__(256) void s2_scan(
    bf16* __restrict__ states, const float* __restrict__ Atot, int b)
{
  const int h  = blockIdx.x >> 4;
  const int p  = ((blockIdx.x & 15) << 2) | (threadIdx.x >> 6);
  const int n0 = (threadIdx.x & 63) * 2;
  __shared__ float ec[64];
  if (threadIdx.x < 64)
    ec[threadIdx.x] = expf(Atot[((size_t)b * 64 + threadIdx.x) * 32 + h]);
  __syncthreads();
  bf16* ptr = states + ((size_t)h * 64 + p) * 128 + n0;
  const size_t cs = (size_t)32 * 8192;   // chunk stride
  float ca = 0.f, cb = 0.f;              // carry pair
  BF2 g0, g1, g2, g3, q0, q1, q2, q3;
  g0.u = *(const uint*)(ptr + 0 * cs);
  g1.u = *(const uint*)(ptr + 1 * cs);
  g2.u = *(const uint*)(ptr + 2 * cs);
  g3.u = *(const uint*)(ptr + 3 * cs);
  for (int g = 0; g < 16; ++g) {
    const int c0 = g * 4;
    if (g < 15) {
      q0.u = *(const uint*)(ptr + (c0 + 4) * cs);
      q1.u = *(const uint*)(ptr + (c0 + 5) * cs);
      q2.u = *(const uint*)(ptr + (c0 + 6) * cs);
      q3.u = *(const uint*)(ptr + (c0 + 7) * cs);
    }
    BF2 o0, o1, o2, o3;
    const float e0 = ec[c0], e1 = ec[c0+1], e2 = ec[c0+2], e3 = ec[c0+3];
    o0.h[0] = __float2bfloat16(ca); o0.h[1] = __float2bfloat16(cb);
    ca = fmaf(e0, ca, __bfloat162float(g0.h[0]));
    cb = fmaf(e0, cb, __bfloat162float(g0.h[1]));
    o1.h[0] = __float2bfloat16(ca); o1.h[1] = __float2bfloat16(cb);
    ca = fmaf(e1, ca, __bfloat162float(g1.h[0]));
    cb = fmaf(e1, cb, __bfloat162float(g1.h[1]));
    o2.h[0] = __float2bfloat16(ca); o2.h[1] = __float2bfloat16(cb);
    ca = fmaf(e2, ca, __bfloat162float(g2.h[0]));
    cb = fmaf(e2, cb, __bfloat162float(g2.h[1]));
    o3.h[0] = __float2bfloat16(ca); o3.h[1] = __float2bfloat16(cb);
    ca = fmaf(e3, ca, __bfloat162float(g3.h[0]));
    cb = fmaf(e3, cb, __bfloat162float(g3.h[1]));
    *(uint*)(ptr + (c0 + 0) * cs) = o0.u;
    *(uint*)(ptr + (c0 + 1) * cs) = o1.u;
    *(uint*)(ptr + (c0 + 2) * cs) = o2.u;
    *(uint*)(ptr + (c0 + 3) * cs) = o3.u;
    g0 = q0; g1 = q1; g2 = q2; g3 = q3;
  }
}

// ---------------- S3: chunk outputs via MFMA -------------------------------
// grid (32 h, 64 c), one batch b. Y written packed ld 2048.
__global__ __launch_bounds__(256) void s3_output(
    const bf16* __restrict__ xBC, const float* __restrict__ dtT,
    const float* __restrict__ A_log, const float* __restrict__ Dp,
    const bf16* __restrict__ states, bf16* __restrict__ Y, int b)
{
  const int hh = blockIdx.x, c = blockIdx.y;
  const int tid = threadIdx.x, lane = tid & 63, wid = tid >> 6;
  __shared__ bf16 Cc[64 * 136];   // [l][n]
  __shared__ bf16 Bc[64 * 136];   // [s][n]; reused as Yb
  __shared__ bf16 Sin[64 * 136];  // [p][n]
  __shared__ bf16 xT[64 * 72];    // [p][l^swz]
  __shared__ bf16 scb[64 * 72];   // [l][s]
  __shared__ float Ac[64], dts[64];
  const size_t r0 = (size_t)b * 4096 + (size_t)c * 64;

  if (tid < 64) {
    float d = dtT[((size_t)(b * 32 + hh)) * 4096 + c * 64 + tid];
    float Ah = -expf(A_log[hh]);
    float v = Ah * d;
    #pragma unroll
    for (int off = 1; off < 64; off <<= 1) {
      float up = __shfl_up(v, off, 64);
      if (tid >= off) v += up;
    }
    Ac[tid] = v; dts[tid] = d;
  }

  #pragma unroll
  for (int k = 0; k < 4; ++k) {
    int id = tid + k * 256, l = id >> 4, n0 = (id & 15) * 8;
    BF8 bv; bv.u = *(const uint4*)(xBC + (r0 + l) * NCONV + 2048 + n0);
    BF8 cv; cv.u = *(const uint4*)(xBC + (r0 + l) * NCONV + 2176 + n0);
    *(uint4*)(Bc + l * 136 + n0) = bv.u;
    *(uint4*)(Cc + l * 136 + n0) = cv.u;
  }
  const bf16* sb = states + ((size_t)c * 32 + hh) * 8192;
  #pragma unroll
  for (int k = 0; k < 4; ++k) {
    int id = tid + k * 256, p = id >> 4, n0 = (id & 15) * 8;
    *(uint4*)(Sin + p * 136 + n0) = *(const uint4*)(sb + p * 128 + n0);
  }
  #pragma unroll
  for (int k = 0; k < 2; ++k) {
    int id = tid + k * 256, l = id >> 3, p0 = (id & 7) * 8;
    BF8 v; v.u = *(const uint4*)(xBC + (r0 + l) * NCONV + hh * 64 + p0);
    #pragma unroll
    for (int j = 0; j < 8; ++j) {
      int p = p0 + j;
      xT[p * 72 + (l ^ swz8(p))] = v.h[j];
    }
  }
  __syncthreads();

  // scores: M=l, N=s, K=n(128); A-frags (C rows) cached for Y_off reuse
  const int wr  = (wid & 1) * 32;   // l
  const int wcs = (wid >> 1) * 32;  // s / p
  f32x4 as[2][2] = {};
  bf16x8_i afrag[2][4];
  #pragma unroll
  for (int ks = 0; ks < 4; ++ks) {
    const int k0 = ks * 32 + (lane >> 4) * 8;
    #pragma unroll
    for (int i = 0; i < 2; ++i)
      afrag[i][ks] =
          *(const bf16x8_i*)(Cc + (wr + i * 16 + (lane & 15)) * 136 + k0);
    #pragma unroll
    for (int j = 0; j < 2; ++j) {
      bf16x8_i bfr =
          *(const bf16x8_i*)(Bc + (wcs + j * 16 + (lane & 15)) * 136 + k0);
      #pragma unroll
      for (int i = 0; i < 2; ++i)
        as[i][j] = __builtin_amdgcn_mfma_f32_16x16x32_bf16(
            afrag[i][ks], bfr, as[i][j], 0, 0, 0);
    }
  }
  const int cr = (lane >> 4) * 4, cc = lane & 15;
  #pragma unroll
  for (int i = 0; i < 2; ++i) {
    #pragma unroll
    for (int r = 0; r < 4; ++r) {
      const int l = wr + i * 16 + cr + r;
      const float acl = Ac[l];
      #pragma unroll
      for (int j = 0; j < 2; ++j) {
        const int s = wcs + j * 16 + cc;
        float val = (s <= l) ? as[i][j][r] * __expf(acl - Ac[s]) * dts[s] : 0.f;
        scb[l * 72 + s] = __float2bfloat16(val);
      }
    }
  }
  __syncthreads();

  // Y_off = C.S_in^T (K=128) scaled by dko_l, += scores.x (K=64)
  f32x4 ay[2][2] = {};
  #pragma unroll
  for (int ks = 0; ks < 4; ++ks) {
    const int k0 = ks * 32 + (lane >> 4) * 8;
    #pragma unroll
    for (int j = 0; j < 2; ++j) {
      bf16x8_i bfr =
          *(const bf16x8_i*)(Sin + (wcs + j * 16 + (lane & 15)) * 136 + k0);
      #pragma unroll
      for (int i = 0; i < 2; ++i)
        ay[i][j] = __builtin_amdgcn_mfma_f32_16x16x32_bf16(
            afrag[i][ks], bfr, ay[i][j], 0, 0, 0);
    }
  }
  #pragma unroll
  for (int i = 0; i < 2; ++i)
    #pragma unroll
    for (int r = 0; r < 4; ++r) {
      const float dk = __expf(Ac[wr + i * 16 + cr + r]);
      #pragma unroll
      for (int j = 0; j < 2; ++j) ay[i][j][r] *= dk;
    }
  #pragma unroll
  for (int ks = 0; ks < 2; ++ks) {
    const int k0 = ks * 32 + (lane >> 4) * 8;
    bf16x8_i a2[2], b2[2];
    #pragma unroll
    for (int i = 0; i < 2; ++i)
      a2[i] = *(const bf16x8_i*)(scb + (wr + i * 16 + (lane & 15)) * 72 + k0);
    #pragma unroll
    for (int j = 0; j < 2; ++j) {
      int p = wcs + j * 16 + (lane & 15);
      b2[j] = *(const bf16x8_i*)(xT + p * 72 + (k0 ^ swz8(p)));
    }
    #pragma unroll
    for (int i = 0; i < 2; ++i)
      #pragma unroll
      for (int j = 0; j < 2; ++j)
        ay[i][j] = __builtin_amdgcn_mfma_f32_16x16x32_bf16(
            a2[i], b2[j], ay[i][j], 0, 0, 0);
  }
  const float Dh = Dp[hh];
  bf16* Yb = Bc;
  #pragma unroll
  for (int i = 0; i < 2; ++i)
    #pragma unroll
    for (int r = 0; r < 4; ++r) {
      const int l = wr + i * 16 + cr + r;
      #pragma unroll
      for (int j = 0; j < 2; ++j) {
        const int p = wcs + j * 16 + cc;
        float xv = __bfloat162float(xT[p * 72 + (l ^ swz8(p))]);
        Yb[l * 136 + p] = __float2bfloat16(ay[i][j][r] + Dh * xv);
      }
    }
  __syncthreads();
  #pragma unroll
  for (int k = 0; k < 2; ++k) {
    int id = tid + k * 256, l = id >> 3, p0 = (id & 7) * 8;
    *(uint4*)(Y + (r0 + l) * 2048 + hh * 64 + p0) =
        *(const uint4*)(Yb + l * 136 + p0);
  }
}

// ---------------- t = rmsnorm(y * silu(z)) * norm_w  (in place over y) -----
__global__ __launch_bounds__(256) void gate_rmsnorm_kernel(
    bf16* __restrict__ y, const bf16* __restrict__ z,
    const float* __restrict__ norm_w)
{
  const size_t row = blockIdx.x;
  const int tid = threadIdx.x;
  __shared__ float red[4];
  const bf16* zr = z + row * 2048;
  bf16* yr = y + row * 2048;
  BF8 zv, yv;
  zv.u = *(const uint4*)(zr + tid * 8);
  yv.u = *(const uint4*)(yr + tid * 8);
  float t[8];
  float local = 0.f;
  #pragma unroll
  for (int j = 0; j < 8; ++j) {
    float zz = __bfloat162float(zv.h[j]);
    float yy = __bfloat162float(yv.h[j]);
    float tv = yy * (zz / (1.f + expf(-zz)));
    t[j] = tv;
    local += tv * tv;
  }
  #pragma unroll
  for (int off = 32; off; off >>= 1) local += __shfl_down(local, off, 64);
  if ((tid & 63) == 0) red[tid >> 6] = local;
  __syncthreads();
  const float total = red[0] + red[1] + red[2] + red[3];
  const float scale = rsqrtf(total * (1.f / 2048.f) + 1e-5f);
  BF8 o;
  #pragma unroll
  for (int j = 0; j < 8; ++j)
    o.h[j] = __float2bfloat16(t[j] * scale * norm_w[tid * 8 + j]);
  *(uint4*)(yr + tid * 8) = o.u;
}

// ---------------------------------------------------------------------------
extern "C" void kernel_launch(void* const* d_in, const int* in_sizes, int n_in,
                              void* d_out, int out_size, void* d_ws, size_t ws_size,
                              hipStream_t stream) {
  (void)in_sizes; (void)n_in; (void)out_size; (void)ws_size;
  const float* u          = (const float*)d_in[0];
  const float* in_proj_w  = (const float*)d_in[1];
  const float* conv_w     = (const float*)d_in[2];
  const float* conv_b     = (const float*)d_in[3];
  const float* dt_bias    = (const float*)d_in[4];
  const float* A_log      = (const float*)d_in[5];
  const float* Dp         = (const float*)d_in[6];
  const float* norm_w     = (const float*)d_in[7];
  const float* out_proj_w = (const float*)d_in[8];
  float* out = (float*)d_out;

  char* ws = (char*)d_ws;
  bf16*  u_bf   = (bf16*)ws;                           //  33,554,432
  bf16*  xpre   = (bf16*)(ws + 33554432);              //  76,546,048
  bf16*  xBCc   = (bf16*)(ws + 110100480);             //  75,497,472
  float* dtT    = (float*)(ws + 185597952);            //   2,097,152
  bf16*  W_xpre = (bf16*)(ws + 187695104);             //   4,784,128
  bf16*  W_z    = (bf16*)(ws + 192479232);             //   4,194,304
  bf16*  w_out  = (bf16*)(ws + 196673536);             //   4,194,304
  float* Atot   = (float*)(ws + 200867840);            //      32,768
  bf16*  states = (bf16*)(ws + 200900608);             //  33,554,432
  bf16*  ybuf   = xpre;                                // y ld 2048 (post-SSD)
  bf16*  zbuf   = xBCc;                                // z ld 2048 (post-SSD)

  // 0) conversions
  cvt_f32_bf16<<<dim3(8192), 256, 0, stream>>>(u, u_bf);
  cvt_f32_bf16<<<dim3(1168), 256, 0, stream>>>(in_proj_w + (size_t)2048*1024,
                                               W_xpre);   // 2336x1024
  cvt_f32_bf16<<<dim3(1024), 256, 0, stream>>>(in_proj_w, W_z);
  cvt_f32_bf16<<<dim3(1024), 256, 0, stream>>>(out_proj_w, w_out);
  // 1) GEMM-X: xpre = u_bf @ W_xpre^T  (N=2336, clamp B rows)
  gemm_bt_mfma<bf16, true><<<dim3(19, 128), 256, 0, stream>>>(
      u_bf, 1024, W_xpre, 1024, xpre, LDXP, 2336, 1024);
  // 2) dt softplus + Atot
  dtsp_atot_kernel<<<dim3(64, 4), 256, 0, stream>>>(xpre, dt_bias, A_log,
                                                    dtT, Atot);
  // 3) conv + silu
  conv_silu_kernel<<<dim3(9, 512, 4), 256, 0, stream>>>(xpre, conv_w, conv_b,
                                                        xBCc);
  // 4) SSD, one batch at a time (states buffer holds one batch)
  for (int b = 0; b < 4; ++b) {
    s1_localstate<<<dim3(32, 64), 256, 0, stream>>>(xBCc, dtT, A_log,
                                                    states, b);
    s2_scan<<<dim3(512), 256, 0, stream>>>(states, Atot, b);
    s3_output<<<dim3(32, 64), 256, 0, stream>>>(xBCc, dtT, A_log, Dp,
                                                states, ybuf, b);
  }
  // 5) GEMM-Z: z = u_bf @ W_z^T (over dead conv buffer)
  gemm_bt_mfma<bf16, false><<<dim3(16, 128), 256, 0, stream>>>(
      u_bf, 1024, W_z, 1024, zbuf, 2048, 2048, 1024);
  // 6) gate + rmsnorm (t over y)
  gate_rmsnorm_kernel<<<dim3(BL), 256, 0, stream>>>(ybuf, zbuf, norm_w);
  // 7) out_proj: out = t @ w_out^T
  gemm_bt_mfma<float, false><<<dim3(8, 128), 256, 0, stream>>>(
      ybuf, 2048, w_out, 2048, out, 1024, 1024, 2048);
}